// Round 16
// baseline (266.593 us; speedup 1.0000x reference)
//
#include <hip/hip_runtime.h>
#include <hip/hip_bf16.h>

#define N_NODES 8192
#define BGRAPH 8
#define NPG 1024
#define DIM 256
#define NH 8
#define DHEAD 32
#define NLAYERS 2
#define INC 128
#define OUTD 64
#define NEDGE 262144
#define DFF 512
#define EPS 1e-5f

typedef __attribute__((ext_vector_type(4))) float f32x4;
typedef __attribute__((ext_vector_type(8))) short s16x8;
typedef __attribute__((ext_vector_type(4))) ushort u16x4;

__device__ __forceinline__ float b2f(ushort u){
  unsigned v = ((unsigned)u) << 16;
  return __builtin_bit_cast(float, v);
}
__device__ __forceinline__ ushort f2b(float f){
  unsigned u = __builtin_bit_cast(unsigned, f);
  u += 0x7fffu + ((u >> 16) & 1u);
  return (ushort)(u >> 16);
}
__device__ __forceinline__ ushort f2b_trunc(float f){
  return (ushort)(__builtin_bit_cast(unsigned, f) >> 16);
}
// async global->LDS, 16B per lane; lds base must be wave-uniform (HW adds lane*16)
__device__ __forceinline__ void gload16(const void* g, void* l){
  __builtin_amdgcn_global_load_lds(
    (const __attribute__((address_space(1))) void*)g,
    (__attribute__((address_space(3))) void*)l,
    16, 0, 0);
}

// ---------------------------------------------------------------------------
// Setup: cast x/weights -> bf16 (sage weights [wl|wr] along K) + degree count
// ---------------------------------------------------------------------------
#define CX  1048576
#define CWI (CX+32768)
#define CSW (CWI+262144)
#define CIW (CSW+393216)
#define COW (CIW+131072)
#define CW1 (COW+262144)
#define CW2 (CW1+262144)   // total 2392064
#define NCAST (CW2/256)
__global__ void k_setup(const float* __restrict__ x, const float* __restrict__ w_in,
    const float* __restrict__ wl, const float* __restrict__ wr,
    const float* __restrict__ iw, const float* __restrict__ ow,
    const float* __restrict__ w1, const float* __restrict__ w2,
    ushort* __restrict__ dst, const int* __restrict__ edst, int* __restrict__ deg){
  if(blockIdx.x >= NCAST){
    int i = (blockIdx.x - NCAST)*256 + threadIdx.x;
    int stride = 512*256;
    for(; i<NEDGE; i+=stride) atomicAdd(&deg[edst[i]], 1);
    return;
  }
  int i = blockIdx.x*256 + threadIdx.x;
  float val;
  if(i < CX)       val = x[i];
  else if(i < CWI) val = w_in[i-CX];
  else if(i < CSW){
    int j = i - CWI;
    int l = j >> 17, r = (j >> 9) & 255, k = j & 511;
    val = (k < 256) ? wl[(l<<16) + (r<<8) + k] : wr[(l<<16) + (r<<8) + (k-256)];
  }
  else if(i < CIW) val = iw[i-CSW];
  else if(i < COW) val = ow[i-CIW];
  else if(i < CW1) val = w1[i-COW];
  else             val = w2[i-CW1];
  dst[i] = f2b(val);
}

__global__ void k_scan(const int* __restrict__ deg, int* __restrict__ offs,
                       float* __restrict__ inv_deg){
  __shared__ int s[1024];
  int t = threadIdx.x;
  int base = t*8;
  int loc[8]; int acc=0;
  #pragma unroll
  for(int j=0;j<8;j++){
    int dv = deg[base+j];
    inv_deg[base+j] = 1.0f/(float)(dv>0?dv:1);
    loc[j]=acc; acc += dv;
  }
  s[t]=acc;
  __syncthreads();
  for(int d=1; d<1024; d<<=1){
    int v = (t>=d)? s[t-d] : 0;
    __syncthreads();
    if(t>=d) s[t]+=v;
    __syncthreads();
  }
  int pre = (t>0)? s[t-1] : 0;
  #pragma unroll
  for(int j=0;j<8;j++) offs[base+j] = pre + loc[j];
  if(t==1023) offs[N_NODES] = s[1023];
}

// ---------------------------------------------------------------------------
// GEMM building blocks (64x64 tile, BK=64)
// ---------------------------------------------------------------------------
#define STAGE_AB(t, buf) do{ \
    int kt_ = (t)*64; \
    _Pragma("unroll") \
    for(int it=0; it<2; ++it){ \
      int c = (wave*2+it)*64 + lane; \
      int row = c >> 3, q = c & 7; \
      int qs = q ^ (row & 7); \
      gload16(A + (size_t)(bm+row)*lda + kt_ + qs*8, (char*)As + (buf)*8192 + (wave*2+it)*1024); \
      gload16(W + (size_t)(bn+row)*K   + kt_ + qs*8, (char*)Bs + (buf)*8192 + (wave*2+it)*1024); \
    } \
  }while(0)

#define MM_COMPUTE(BUFOFF) \
      _Pragma("unroll") \
      for(int kk=0; kk<2; ++kk){ \
        s16x8 af[2], bfr[2]; \
        _Pragma("unroll") \
        for(int mi=0; mi<2; ++mi){ \
          int row = wr*32 + mi*16 + l15; \
          int col = (kk*64 + l4*16) ^ ((row & 7) << 4); \
          af[mi] = *(const s16x8*)((const char*)As + (BUFOFF) + row*128 + col); \
        } \
        _Pragma("unroll") \
        for(int nj=0; nj<2; ++nj){ \
          int row = wc*32 + nj*16 + l15; \
          int col = (kk*64 + l4*16) ^ ((row & 7) << 4); \
          bfr[nj] = *(const s16x8*)((const char*)Bs + (BUFOFF) + row*128 + col); \
        } \
        _Pragma("unroll") \
        for(int mi=0; mi<2; ++mi) \
          _Pragma("unroll") \
          for(int nj=0; nj<2; ++nj) \
            acc[mi][nj] = __builtin_amdgcn_mfma_f32_16x16x32_bf16(af[mi], bfr[nj], acc[mi][nj], 0,0,0); \
      }

// double-buffered loop (standalone GEMMs)
#define MM_LOOP \
  f32x4 acc[2][2] = {}; \
  { const int nt = K >> 6; \
    STAGE_AB(0, 0); \
    asm volatile("s_waitcnt vmcnt(0)" ::: "memory"); \
    __builtin_amdgcn_s_barrier(); \
    int cur = 0; \
    for(int t=0; t<nt; ++t){ \
      if(t+1 < nt) STAGE_AB(t+1, cur^1); \
      MM_COMPUTE(cur*8192) \
      asm volatile("s_waitcnt vmcnt(0)" ::: "memory"); \
      __builtin_amdgcn_s_barrier(); \
      cur ^= 1; \
    } \
  }

// single-buffered loop (merged kernels: minimal LDS union)
#define MM_LOOP_SB \
  f32x4 acc[2][2] = {}; \
  { const int nt = K >> 6; \
    for(int t=0; t<nt; ++t){ \
      __syncthreads(); \
      STAGE_AB(t, 0); \
      asm volatile("s_waitcnt vmcnt(0)" ::: "memory"); \
      __builtin_amdgcn_s_barrier(); \
      MM_COMPUTE(0) \
    } \
  }

// generic GEMM: bf16 resid (ldrb) + bf16 out + optional BN stats
template<bool RELU, bool RESIDB, bool BIAS, bool WBF, bool STATS>
__global__ __launch_bounds__(256) void k_mm(const ushort* __restrict__ A,
    const ushort* __restrict__ W, const float* __restrict__ bias,
    const ushort* __restrict__ residb, ushort* __restrict__ Cb,
    float* __restrict__ gS, float* __restrict__ gQ,
    int M, int Nc, int K, int lda, int ldcb, int ldrb)
{
  __shared__ ushort As[2*64*64];
  __shared__ ushort Bs[2*64*64];
  __shared__ float sredS[64];
  __shared__ float sredQ[64];
  const int tid = threadIdx.x;
  const int lane = tid & 63, wave = tid >> 6;
  const int l15 = lane & 15, l4 = lane >> 4;
  const int bm = blockIdx.y*64, bn = blockIdx.x*64;
  const int wr = wave >> 1, wc = wave & 1;
  MM_LOOP

  float sloc[2] = {0.f,0.f}, qloc[2] = {0.f,0.f};
  #pragma unroll
  for(int mi=0; mi<2; ++mi){
    #pragma unroll
    for(int nj=0; nj<2; ++nj){
      int col = bn + wc*32 + nj*16 + l15;
      float bv = BIAS ? bias[col] : 0.f;
      #pragma unroll
      for(int r=0; r<4; ++r){
        int row = bm + wr*32 + mi*16 + l4*4 + r;
        float v = acc[mi][nj][r] + bv;
        if(RESIDB) v += b2f(residb[(size_t)row*ldrb + col]);
        if(RELU)   v = fmaxf(v, 0.f);
        if(WBF)    Cb[(size_t)row*ldcb + col] = f2b(v);
        if(STATS){ sloc[nj] += v; qloc[nj] += v*v; }
      }
    }
  }
  if(STATS){
    if(tid < 64){ sredS[tid]=0.f; sredQ[tid]=0.f; }
    __syncthreads();
    int c0 = wc*32 + l15;
    atomicAdd(&sredS[c0],    sloc[0]); atomicAdd(&sredQ[c0],    qloc[0]);
    atomicAdd(&sredS[c0+16], sloc[1]); atomicAdd(&sredQ[c0+16], qloc[1]);
    __syncthreads();
    if(tid < 64){
      atomicAdd(&gS[bn+tid], sredS[tid]);
      atomicAdd(&gQ[bn+tid], sredQ[tid]);
    }
  }
}

// ---------------------------------------------------------------------------
// Merged: CSR fill (blocks [0,512)) ∪ in_proj GEMM ([512,1024)), 16KB union
// ---------------------------------------------------------------------------
__global__ __launch_bounds__(256) void k_fill_inproj(const int* __restrict__ src,
    const int* __restrict__ dst, const int* __restrict__ offs,
    int* __restrict__ cursor, int* __restrict__ csr,
    const ushort* __restrict__ xb, const ushort* __restrict__ w_in_b,
    const float* __restrict__ b_in, ushort* __restrict__ hwb)
{
  __shared__ __align__(16) char smem[16384];
  const int tid = threadIdx.x;
  if(blockIdx.x < 512){
    int i = blockIdx.x*256 + tid;
    for(; i<NEDGE; i+=512*256){
      int d = dst[i];
      int p = atomicAdd(&cursor[d], 1);
      csr[offs[d]+p] = src[i];
    }
  } else {
    int idx = blockIdx.x - 512;
    const int lane = tid & 63, wave = tid >> 6;
    const int l15 = lane & 15, l4 = lane >> 4;
    const int bn = (idx & 3)*64, bm = (idx >> 2)*64;
    const int wr = wave >> 1, wc = wave & 1;
    const ushort* A = xb;
    const ushort* W = w_in_b;
    const int K = INC, lda = INC;
    ushort* As = (ushort*)smem;
    ushort* Bs = As + 4096;
    MM_LOOP_SB
    #pragma unroll
    for(int mi=0; mi<2; ++mi){
      #pragma unroll
      for(int nj=0; nj<2; ++nj){
        int col = bn + wc*32 + nj*16 + l15;
        float bv = b_in[col];
        #pragma unroll
        for(int r=0; r<4; ++r){
          int row = bm + wr*32 + mi*16 + l4*4 + r;
          hwb[(size_t)row*512 + 256 + col] = f2b(acc[mi][nj][r] + bv);
        }
      }
    }
  }
}

// ---------------------------------------------------------------------------
// Merged dispatch 1: aggregate (blocks [0,2048)) ∪ QKV GEMM ([2048,3584))
// QKV epilogue writes PACKED per-(graph,head) q/k/vpack[64][1024][32]
// ---------------------------------------------------------------------------
__global__ __launch_bounds__(256) void k_agg_qkv(ushort* __restrict__ hwb,
    const int* __restrict__ offs, const int* __restrict__ csr,
    const float* __restrict__ inv_deg, const ushort* __restrict__ iwb,
    const float* __restrict__ attn_ib, ushort* __restrict__ qpack,
    ushort* __restrict__ kpack, ushort* __restrict__ vpack)
{
  __shared__ __align__(16) char smem[16384];
  const int tid = threadIdx.x;
  const int lane = tid & 63, wave = tid >> 6;
  if(blockIdx.x < 2048){
    // ---- aggregate: one node per wave ----
    int n = blockIdx.x*4 + wave;
    int beg = offs[n], end = offs[n+1];
    f32x4 a0 = {0,0,0,0}, a1 = {0,0,0,0}, a2 = {0,0,0,0}, a3 = {0,0,0,0};
    int i = beg;
    for(; i+4<=end; i+=4){
      int j0=csr[i], j1=csr[i+1], j2=csr[i+2], j3=csr[i+3];
      u16x4 v0 = *(const u16x4*)(hwb + (size_t)j0*512 + 256 + lane*4);
      u16x4 v1 = *(const u16x4*)(hwb + (size_t)j1*512 + 256 + lane*4);
      u16x4 v2 = *(const u16x4*)(hwb + (size_t)j2*512 + 256 + lane*4);
      u16x4 v3 = *(const u16x4*)(hwb + (size_t)j3*512 + 256 + lane*4);
      #pragma unroll
      for(int c=0;c<4;c++){ a0[c]+=b2f(v0[c]); a1[c]+=b2f(v1[c]);
                            a2[c]+=b2f(v2[c]); a3[c]+=b2f(v3[c]); }
    }
    for(; i<end; ++i){
      int j0=csr[i];
      u16x4 v0 = *(const u16x4*)(hwb + (size_t)j0*512 + 256 + lane*4);
      #pragma unroll
      for(int c=0;c<4;c++) a0[c]+=b2f(v0[c]);
    }
    float inv = inv_deg[n];
    u16x4 outv;
    #pragma unroll
    for(int c=0;c<4;c++) outv[c] = f2b((a0[c]+a1[c]+a2[c]+a3[c])*inv);
    *(u16x4*)(hwb + (size_t)n*512 + lane*4) = outv;
  } else {
    // ---- QKV GEMM: A = H (hwb right half, lda=512), W = iwb, Nc=768 ----
    int idx = blockIdx.x - 2048;
    const int bn = (idx % 12)*64, bm = (idx / 12)*64;
    const int l15 = lane & 15, l4 = lane >> 4;
    const int wr = wave >> 1, wc = wave & 1;
    const ushort* A = hwb + 256;
    const ushort* W = iwb;
    const int K = 256, lda = 512;
    ushort* As = (ushort*)smem;
    ushort* Bs = As + 4096;
    MM_LOOP_SB
    const int bgq = bm >> 10;   // 64-row block never crosses a graph boundary
    #pragma unroll
    for(int mi=0; mi<2; ++mi){
      #pragma unroll
      for(int nj=0; nj<2; ++nj){
        int col = bn + wc*32 + nj*16 + l15;
        float bv = attn_ib[col];
        int part = col >> 8;            // 0=Q 1=K 2=V
        int hh = (col >> 5) & 7;
        int dd = col & 31;
        ushort* dstp = (part==0 ? qpack : (part==1 ? kpack : vpack))
                     + (size_t)(bgq*8 + hh)*32768 + dd;
        #pragma unroll
        for(int r=0; r<4; ++r){
          int rig = (bm + wr*32 + mi*16 + l4*4 + r) & 1023;
          dstp[rig*32] = f2b(acc[mi][nj][r] + bv);
        }
      }
    }
  }
}

// ---------------------------------------------------------------------------
// Merged dispatch 2: attention (blocks [0,512)) ∪ SAGE GEMM ([512,1024))
// Attention: 32 queries/wave (2 Q-frags share each staged K-tile and V-frag),
// 128 queries/block -> 512 blocks; staging traffic + barriers halved.
// ---------------------------------------------------------------------------
__global__ __launch_bounds__(256) void k_attn_sage(const ushort* __restrict__ qpack,
    const ushort* __restrict__ kpack, const ushort* __restrict__ vpack,
    ushort* __restrict__ attnO, const ushort* __restrict__ hwb,
    const ushort* __restrict__ swb, const float* __restrict__ sage_bl,
    ushort* __restrict__ locB, float* __restrict__ gS, float* __restrict__ gQ)
{
  __shared__ __align__(16) char smem[20992];
  const int tid = threadIdx.x;
  const int lane = tid & 63, wave = tid >> 6;
  const int l15 = lane & 15;
  if(blockIdx.x < 512){
    // ---- flash attention (3-buf Ks, 2-buf Vt, 1 barrier/tile, 2 Q-frags) ----
    ushort* KsB = (ushort*)smem;          // 3 x 2048 ushorts
    ushort* VtB = (ushort*)smem + 6144;   // 2 x 2048 ushorts
    const int g = lane >> 4;
    int bid = blockIdx.x;
    int h  = bid & 7;
    int bg = (bid >> 3) & 7;
    int qc = bid >> 6;                    // [0,8)
    const int bgh = bid & 63;
    const int nb = bg*NPG + qc*128 + wave*32;
    const ushort* qp = qpack + (size_t)bgh*32768;
    const ushort* kp = kpack + (size_t)bgh*32768;
    const ushort* vp = vpack + (size_t)bgh*32768;

    const int rho = tid >> 2, qq = tid & 3;
    const int grp = rho >> 5, r32 = rho & 31;
    const int tt = r32 >> 4, wi = r32 & 15;
    const int jperm = grp*32 + (wi >> 2)*8 + tt*4 + (wi & 3);
    const int qs = qq ^ ((rho >> 1) & 3);

    const int qrow = qc*128 + wave*32 + l15;
    s16x8 qf0 = *(const s16x8*)(qp + (size_t)qrow*32 + g*8);
    s16x8 qf1 = *(const s16x8*)(qp + (size_t)(qrow+16)*32 + g*8);
    {
      const float scale2 = 0.2550370703637335f;   // 1/sqrt(32) * log2(e)
      #pragma unroll
      for(int i=0;i<8;i++){
        qf0[i] = (short)f2b(b2f((ushort)qf0[i]) * scale2);
        qf1[i] = (short)f2b(b2f((ushort)qf1[i]) * scale2);
      }
    }
    f32x4 o0 = {0.f,0.f,0.f,0.f}, o1 = {0.f,0.f,0.f,0.f};
    f32x4 o2 = {0.f,0.f,0.f,0.f}, o3 = {0.f,0.f,0.f,0.f};
    float mrun0 = -1e30f, lrun0 = 0.f;
    float mrun1 = -1e30f, lrun1 = 0.f;

    gload16(kp + (size_t)jperm*32 + qs*8, (char*)KsB + wave*1024);
    s16x8 vcur = *(const s16x8*)(vp + (size_t)lane*32 + wave*8);

    for(int st=0; st<16; ++st){
      int vb = st & 1;
      int kbuf = st % 3;
      ushort* vtb = VtB + vb*2048;
      #pragma unroll
      for(int i=0;i<8;i++){
        int d = wave*8 + i;
        vtb[d*64 + (lane ^ (i<<3))] = (ushort)vcur[i];
      }
      s16x8 vnext = vcur;
      if(st+1 < 16){
        gload16(kp + (size_t)((st+1)*64 + jperm)*32 + qs*8,
                (char*)(KsB + ((st+1)%3)*2048) + wave*1024);
        vnext = *(const s16x8*)(vp + (size_t)((st+1)*64 + lane)*32 + wave*8);
      }
      asm volatile("s_waitcnt lgkmcnt(0)" ::: "memory");
      __builtin_amdgcn_s_barrier();

      const char* ksb = (const char*)(KsB + kbuf*2048);
      f32x4 sc0[4], sc1[4];
      __builtin_amdgcn_s_setprio(1);
      #pragma unroll
      for(int q4=0; q4<4; ++q4){
        int r0 = q4*16 + l15;
        s16x8 kf = *(const s16x8*)(ksb + r0*64 + ((g*16) ^ (((r0>>1)&3)<<4)));
        f32x4 z = {0.f,0.f,0.f,0.f};
        sc0[q4] = __builtin_amdgcn_mfma_f32_16x16x32_bf16(kf, qf0, z, 0,0,0);
        sc1[q4] = __builtin_amdgcn_mfma_f32_16x16x32_bf16(kf, qf1, z, 0,0,0);
      }
      __builtin_amdgcn_s_setprio(0);

      // ---- softmax set0 ----
      float smax = -1e30f;
      #pragma unroll
      for(int q4=0; q4<4; ++q4)
        #pragma unroll
        for(int r=0; r<4; ++r) smax = fmaxf(smax, sc0[q4][r]);
      smax = fmaxf(smax, __shfl_xor(smax, 16));
      smax = fmaxf(smax, __shfl_xor(smax, 32));
      if(!__all((int)(smax <= mrun0 + 8.0f))){
        float mnew = fmaxf(mrun0, smax);
        float alpha = exp2f(mrun0 - mnew);
        lrun0 *= alpha;
        #pragma unroll
        for(int r=0;r<4;r++){
          float ar = __shfl(alpha, (lane & 48) | (g*4 + r), 64);
          o0[r] *= ar; o1[r] *= ar;
        }
        mrun0 = mnew;
      }
      s16x8 pa00, pa01;
      {
        float ps = 0.f;
        float p[16];
        #pragma unroll
        for(int q4=0; q4<4; ++q4)
          #pragma unroll
          for(int r=0; r<4; ++r){
            float pv = exp2f(sc0[q4][r] - mrun0);
            p[q4*4+r] = pv; ps += pv;
          }
        ps += __shfl_xor(ps, 16);
        ps += __shfl_xor(ps, 32);
        lrun0 += ps;
        #pragma unroll
        for(int i=0;i<8;i++){ pa00[i] = (short)f2b_trunc(p[i]); pa01[i] = (short)f2b_trunc(p[8+i]); }
      }
      // ---- softmax set1 ----
      float smax1 = -1e30f;
      #pragma unroll
      for(int q4=0; q4<4; ++q4)
        #pragma unroll
        for(int r=0; r<4; ++r) smax1 = fmaxf(smax1, sc1[q4][r]);
      smax1 = fmaxf(smax1, __shfl_xor(smax1, 16));
      smax1 = fmaxf(smax1, __shfl_xor(smax1, 32));
      if(!__all((int)(smax1 <= mrun1 + 8.0f))){
        float mnew = fmaxf(mrun1, smax1);
        float alpha = exp2f(mrun1 - mnew);
        lrun1 *= alpha;
        #pragma unroll
        for(int r=0;r<4;r++){
          float ar = __shfl(alpha, (lane & 48) | (g*4 + r), 64);
          o2[r] *= ar; o3[r] *= ar;
        }
        mrun1 = mnew;
      }
      s16x8 pa10, pa11;
      {
        float ps = 0.f;
        float p[16];
        #pragma unroll
        for(int q4=0; q4<4; ++q4)
          #pragma unroll
          for(int r=0; r<4; ++r){
            float pv = exp2f(sc1[q4][r] - mrun1);
            p[q4*4+r] = pv; ps += pv;
          }
        ps += __shfl_xor(ps, 16);
        ps += __shfl_xor(ps, 32);
        lrun1 += ps;
        #pragma unroll
        for(int i=0;i<8;i++){ pa10[i] = (short)f2b_trunc(p[i]); pa11[i] = (short)f2b_trunc(p[8+i]); }
      }

      const char* vtc = (const char*)(VtB + vb*2048);
      int colb0 = g*16, colb1 = 64 + g*16;
      int d0 = l15, d1 = l15 + 16;
      s16x8 v00 = *(const s16x8*)(vtc + d0*128 + (colb0 ^ ((d0&7)<<4)));
      s16x8 v01 = *(const s16x8*)(vtc + d1*128 + (colb0 ^ ((d1&7)<<4)));
      s16x8 v10 = *(const s16x8*)(vtc + d0*128 + (colb1 ^ ((d0&7)<<4)));
      s16x8 v11 = *(const s16x8*)(vtc + d1*128 + (colb1 ^ ((d1&7)<<4)));
      __builtin_amdgcn_s_setprio(1);
      o0 = __builtin_amdgcn_mfma_f32_16x16x32_bf16(pa00, v00, o0, 0,0,0);
      o1 = __builtin_amdgcn_mfma_f32_16x16x32_bf16(pa00, v01, o1, 0,0,0);
      o0 = __builtin_amdgcn_mfma_f32_16x16x32_bf16(pa01, v10, o0, 0,0,0);
      o1 = __builtin_amdgcn_mfma_f32_16x16x32_bf16(pa01, v11, o1, 0,0,0);
      o2 = __builtin_amdgcn_mfma_f32_16x16x32_bf16(pa10, v00, o2, 0,0,0);
      o3 = __builtin_amdgcn_mfma_f32_16x16x32_bf16(pa10, v01, o3, 0,0,0);
      o2 = __builtin_amdgcn_mfma_f32_16x16x32_bf16(pa11, v10, o2, 0,0,0);
      o3 = __builtin_amdgcn_mfma_f32_16x16x32_bf16(pa11, v11, o3, 0,0,0);
      __builtin_amdgcn_s_setprio(0);

      vcur = vnext;
    }
    float inv0 = 1.0f/lrun0;
    float inv1 = 1.0f/lrun1;
    #pragma unroll
    for(int r=0;r<4;r++){
      int q2 = g*4 + r;
      float ir0 = __shfl(inv0, (lane & 48) | q2, 64);
      float ir1 = __shfl(inv1, (lane & 48) | q2, 64);
      size_t nrow0 = (size_t)(nb + q2)*DIM + h*32;
      size_t nrow1 = (size_t)(nb + 16 + q2)*DIM + h*32;
      attnO[nrow0 + l15]      = f2b(o0[r]*ir0);
      attnO[nrow0 + 16 + l15] = f2b(o1[r]*ir0);
      attnO[nrow1 + l15]      = f2b(o2[r]*ir1);
      attnO[nrow1 + 16 + l15] = f2b(o3[r]*ir1);
    }
  } else {
    // ---- SAGE GEMM: A=[agg|H] K=512, +bias +H resid (bf16), BN1 stats -> locB ----
    int idx = blockIdx.x - 512;
    const int bn = (idx & 3)*64, bm = (idx >> 2)*64;
    const int l4 = lane >> 4;
    const int wr = wave >> 1, wc = wave & 1;
    const ushort* A = hwb;
    const ushort* W = swb;
    const int K = 512, lda = 512;
    ushort* As = (ushort*)smem;
    ushort* Bs = As + 4096;
    float* sredS = (float*)(smem + 16384);
    float* sredQ = sredS + 64;
    MM_LOOP_SB

    float sloc[2] = {0.f,0.f}, qloc[2] = {0.f,0.f};
    #pragma unroll
    for(int mi=0; mi<2; ++mi){
      #pragma unroll
      for(int nj=0; nj<2; ++nj){
        int col = bn + wc*32 + nj*16 + l15;
        float bv = sage_bl[col];
        #pragma unroll
        for(int r=0; r<4; ++r){
          int row = bm + wr*32 + mi*16 + l4*4 + r;
          float v = acc[mi][nj][r] + bv + b2f(hwb[(size_t)row*512 + 256 + col]);
          locB[(size_t)row*DIM + col] = f2b(v);
          sloc[nj] += v; qloc[nj] += v*v;
        }
      }
    }
    if(tid < 64){ sredS[tid]=0.f; sredQ[tid]=0.f; }
    __syncthreads();
    int c0 = wc*32 + l15;
    atomicAdd(&sredS[c0],    sloc[0]); atomicAdd(&sredQ[c0],    qloc[0]);
    atomicAdd(&sredS[c0+16], sloc[1]); atomicAdd(&sredQ[c0+16], qloc[1]);
    __syncthreads();
    if(tid < 64){
      atomicAdd(&gS[bn+tid], sredS[tid]);
      atomicAdd(&gQ[bn+tid], sredQ[tid]);
    }
  }
}

// ---------------------------------------------------------------------------
// Vectorized BN applies (u16x4/f32x4). slot: [s1|q1|s2|q2|s3|q3] x 256 floats
// ---------------------------------------------------------------------------
__global__ __launch_bounds__(256) void k_apply12(const ushort* __restrict__ locB,
    const ushort* __restrict__ globB, const float* __restrict__ slot,
    const float* __restrict__ n1w, const float* __restrict__ n1b,
    const float* __restrict__ n2w, const float* __restrict__ n2b,
    ushort* __restrict__ combB){
  int t = blockIdx.x*256 + threadIdx.x;
  int base = t*4;
  int d0 = base & 255;
  u16x4 lv = *(const u16x4*)(locB + base);
  u16x4 gv = *(const u16x4*)(globB + base);
  f32x4 s1 = *(const f32x4*)(slot + d0);
  f32x4 q1 = *(const f32x4*)(slot + 256 + d0);
  f32x4 s2 = *(const f32x4*)(slot + 512 + d0);
  f32x4 q2 = *(const f32x4*)(slot + 768 + d0);
  f32x4 w1v = *(const f32x4*)(n1w + d0);
  f32x4 b1v = *(const f32x4*)(n1b + d0);
  f32x4 w2v = *(const f32x4*)(n2w + d0);
  f32x4 b2v = *(const f32x4*)(n2b + d0);
  const float invn = 1.0f/N_NODES;
  u16x4 outv;
  #pragma unroll
  for(int c=0;c<4;c++){
    float m1 = s1[c]*invn, v1 = q1[c]*invn - m1*m1;
    float m2 = s2[c]*invn, v2 = q2[c]*invn - m2*m2;
    float y1 = (b2f(lv[c])-m1)*rsqrtf(v1+EPS)*w1v[c] + b1v[c];
    float y2 = (b2f(gv[c])-m2)*rsqrtf(v2+EPS)*w2v[c] + b2v[c];
    outv[c] = f2b(y1 + y2);
  }
  *(u16x4*)(combB + base) = outv;
}

// BN3 + outer BN + relu + residual (closed form; vectorized, bf16 state)
__global__ __launch_bounds__(256) void k_apply3o(const ushort* __restrict__ xB,
    const float* __restrict__ slot, const float* __restrict__ n3w,
    const float* __restrict__ bw, const float* __restrict__ bb,
    ushort* __restrict__ hwbR){
  int t = blockIdx.x*256 + threadIdx.x;
  int base = t*4;
  int d0 = base & 255;
  int row = base >> 8;
  u16x4 xv = *(const u16x4*)(xB + base);
  u16x4 hv = *(const u16x4*)(hwbR + (size_t)row*512 + d0);
  f32x4 s3 = *(const f32x4*)(slot + 1024 + d0);
  f32x4 q3 = *(const f32x4*)(slot + 1280 + d0);
  f32x4 wv3 = *(const f32x4*)(n3w + d0);
  f32x4 bwv = *(const f32x4*)(bw + d0);
  f32x4 bbv = *(const f32x4*)(bb + d0);
  const float invn = 1.0f/N_NODES;
  u16x4 outv;
  #pragma unroll
  for(int c=0;c<4;c++){
    float m = s3[c]*invn, var = q3[c]*invn - m*m;
    float rs = rsqrtf(var+EPS);
    float gch = rs*wv3[c];
    float rso = rsqrtf(gch*gch*var + EPS);
    float yo = (b2f(xv[c])-m)*gch*rso*bwv[c] + bbv[c];
    outv[c] = f2b(b2f(hv[c]) + fmaxf(yo, 0.f));
  }
  *(u16x4*)(hwbR + (size_t)row*512 + d0) = outv;
}

// ---------------------------------------------------------------------------
// Pooling (bf16 H) + head
// ---------------------------------------------------------------------------
__global__ void k_pool(const ushort* __restrict__ hwbR, float* __restrict__ pooled){
  int b = blockIdx.x, c = blockIdx.y, d = threadIdx.x;
  int r0 = c*64;
  float s=0.f;
  for(int i=0;i<64;i++) s += b2f(hwbR[(size_t)(b*NPG + r0 + i)*512 + d]);
  atomicAdd(&pooled[b*DIM+d], s*(1.0f/NPG));
}
__global__ void k_out(const float* __restrict__ pooled, const float* __restrict__ w_out,
                      const float* __restrict__ b_out, float* __restrict__ out){
  int t = threadIdx.x;
  if(t >= BGRAPH*OUTD) return;
  int b = t/OUTD, oc = t%OUTD;
  float s = b_out[oc];
  for(int k=0;k<DIM;k++) s += pooled[b*DIM+k]*w_out[oc*DIM+k];
  out[t] = s;
}

// ---------------------------------------------------------------------------
// Orchestration
// ---------------------------------------------------------------------------
extern "C" void kernel_launch(void* const* d_in, const int* in_sizes, int n_in,
                              void* d_out, int out_size, void* d_ws, size_t ws_size,
                              hipStream_t stream) {
  const float* x       = (const float*)d_in[0];
  const int*   edge    = (const int*)d_in[1];
  const float* w_in    = (const float*)d_in[3];
  const float* b_in    = (const float*)d_in[4];
  const float* sage_wl = (const float*)d_in[5];
  const float* sage_bl = (const float*)d_in[6];
  const float* sage_wr = (const float*)d_in[7];
  const float* attn_iw = (const float*)d_in[8];
  const float* attn_ib = (const float*)d_in[9];
  const float* attn_ow = (const float*)d_in[10];
  const float* attn_ob = (const float*)d_in[11];
  const float* n1_w = (const float*)d_in[12];
  const float* n1_b = (const float*)d_in[13];
  const float* n2_w = (const float*)d_in[14];
  const float* n2_b = (const float*)d_in[15];
  const float* n3_w = (const float*)d_in[16];
  const float* n3_b = (const float*)d_in[17];
  const float* mlp_w1 = (const float*)d_in[18];
  const float* mlp_b1 = (const float*)d_in[19];
  const float* mlp_w2 = (const float*)d_in[20];
  const float* mlp_b2 = (const float*)d_in[21];
  const float* bn_w = (const float*)d_in[22];
  const float* bn_b = (const float*)d_in[23];
  const float* w_out = (const float*)d_in[24];
  const float* b_out = (const float*)d_in[25];

  const size_t ND = (size_t)N_NODES*DIM;        // 2,097,152
  ushort* wsb   = (ushort*)d_ws;
  ushort* locB  = wsb;             // [N][256] bf16
  ushort* globB = wsb + ND;        // [N][256] bf16
  ushort* hwb   = wsb + 2*ND;      // [N][512] : [agg | H] bf16
  ushort* qpack = wsb + 4*ND;      // [64][1024][32]
  ushort* kpack = wsb + 5*ND;      // [64][1024][32]
  ushort* vpack = wsb + 6*ND;      // [64][1024][32]
  ushort* attnOb= wsb + 7*ND;      // [N][256]
  ushort* combb = wsb + 8*ND;      // [N][256]
  ushort* hidb  = wsb + 9*ND;      // [N][512]
  ushort* castb = wsb + 11*ND;     // CW2 elems
  ushort* xb     = castb;
  ushort* w_in_b = castb + CX;
  ushort* sageWb = castb + CWI;
  ushort* iw_b   = castb + CSW;
  ushort* ow_b   = castb + CIW;
  ushort* w1_b   = castb + COW;
  ushort* w2_b   = castb + CW1;
  float* mf      = (float*)(castb + CW2);
  float* inv_deg = mf;                       // 8192
  float* bnslots = mf + 8192;                // 3072 (zeroed)
  float* pooled  = bnslots + 3072;           // 2048 (zeroed)
  int* deg    = (int*)(pooled + 2048);       // 8192 (zeroed)
  int* cursor = deg + N_NODES;               // 8192 (zeroed)
  int* offs   = cursor + N_NODES;            // 8193 (+pad)
  int* csr    = offs + N_NODES + 8;

  const int* esrc = edge;
  const int* edst = edge + NEDGE;

  // zero bnslots + pooled + deg + cursor (contiguous)
  hipMemsetAsync(bnslots, 0, (3072+2048)*sizeof(float) + 2*N_NODES*sizeof(int), stream);

  k_setup<<<NCAST+512,256,0,stream>>>(x, w_in, sage_wl, sage_wr, attn_iw,
      attn_ow, mlp_w1, mlp_w2, castb, edst, deg);
  k_scan<<<1,1024,0,stream>>>(deg, offs, inv_deg);

  // CSR fill ∪ in_proj (both ready after scan)
  k_fill_inproj<<<1024,256,0,stream>>>(esrc, edst, offs, cursor, csr,
      xb, w_in_b, b_in, hwb);

  for(int l=0; l<NLAYERS; ++l){
    const ushort* swb = sageWb + (size_t)l*131072;   // [256][512] = [wl|wr]
    const ushort* iwb = iw_b + (size_t)l*196608;
    const ushort* owb = ow_b + (size_t)l*65536;
    const ushort* w1b = w1_b + (size_t)l*131072;
    const ushort* w2b = w2_b + (size_t)l*131072;
    float* slot = bnslots + (size_t)l*1536;

    // D1: aggregate ∪ QKV GEMM (packed q/k/v output)
    k_agg_qkv<<<3584,256,0,stream>>>(hwb, offs, csr, inv_deg, iwb,
        attn_ib + l*3*DIM, qpack, kpack, vpack);

    // D2: attention (32 q/wave) ∪ SAGE GEMM (bf16 H resid, BN1 stats)
    k_attn_sage<<<1024,256,0,stream>>>(qpack, kpack, vpack, attnOb, hwb, swb,
        sage_bl + l*DIM, locB, slot, slot+256);

    // out-proj (+bf16 H resid, BN2 stats) -> globB
    k_mm<false,true,true,true,true><<<dim3(4,128),256,0,stream>>>(
        attnOb, owb, attn_ob + l*DIM, hwb+256, globB, slot+512, slot+768,
        N_NODES, DIM, DIM, DIM, DIM, 512);

    // comb = BN1(loc) + BN2(glob)
    k_apply12<<<2048,256,0,stream>>>(locB, globB, slot,
        n1_w + l*DIM, n1_b + l*DIM, n2_w + l*DIM, n2_b + l*DIM, combb);

    // MLP1: hid = relu(comb@w1^T+b1) -> hidb
    k_mm<true,false,true,true,false><<<dim3(8,128),256,0,stream>>>(
        combb, w1b, mlp_b1 + l*DFF, nullptr, hidb, nullptr, nullptr,
        N_NODES, DFF, DIM, DIM, 512, 256);

    // MLP2: out2 = comb + hid@w2^T + b2 (+BN3 stats) -> globB
    k_mm<false,true,true,true,true><<<dim3(4,128),256,0,stream>>>(
        hidb, w2b, mlp_b2 + l*DIM, combb, globB, slot+1024, slot+1280,
        N_NODES, DIM, 512, 512, DIM, 256);

    // BN3 + outer BN + relu + residual -> hwb right half (bf16 H)
    k_apply3o<<<2048,256,0,stream>>>(globB, slot, n3_w + l*DIM,
        bn_w + l*DIM, bn_b + l*DIM, hwb+256);
  }

  k_pool<<<dim3(BGRAPH, NPG/64),256,0,stream>>>(hwb+256, pooled);
  k_out<<<1,512,0,stream>>>(pooled, w_out, b_out, (float*)d_out);
}

// Round 17
// 259.184 us; speedup vs baseline: 1.0286x; 1.0286x over previous
//
#include <hip/hip_runtime.h>
#include <hip/hip_bf16.h>

#define N_NODES 8192
#define BGRAPH 8
#define NPG 1024
#define DIM 256
#define NH 8
#define DHEAD 32
#define NLAYERS 2
#define INC 128
#define OUTD 64
#define NEDGE 262144
#define DFF 512
#define EPS 1e-5f

typedef __attribute__((ext_vector_type(4))) float f32x4;
typedef __attribute__((ext_vector_type(8))) short s16x8;
typedef __attribute__((ext_vector_type(4))) ushort u16x4;

__device__ __forceinline__ float b2f(ushort u){
  unsigned v = ((unsigned)u) << 16;
  return __builtin_bit_cast(float, v);
}
__device__ __forceinline__ ushort f2b(float f){
  unsigned u = __builtin_bit_cast(unsigned, f);
  u += 0x7fffu + ((u >> 16) & 1u);
  return (ushort)(u >> 16);
}
__device__ __forceinline__ ushort f2b_trunc(float f){
  return (ushort)(__builtin_bit_cast(unsigned, f) >> 16);
}
// async global->LDS, 16B per lane; lds base must be wave-uniform (HW adds lane*16)
__device__ __forceinline__ void gload16(const void* g, void* l){
  __builtin_amdgcn_global_load_lds(
    (const __attribute__((address_space(1))) void*)g,
    (__attribute__((address_space(3))) void*)l,
    16, 0, 0);
}

// ---------------------------------------------------------------------------
// Setup: cast x/weights -> bf16 (sage weights [wl|wr] along K) + degree count
// ---------------------------------------------------------------------------
#define CX  1048576
#define CWI (CX+32768)
#define CSW (CWI+262144)
#define CIW (CSW+393216)
#define COW (CIW+131072)
#define CW1 (COW+262144)
#define CW2 (CW1+262144)   // total 2392064
#define NCAST (CW2/256)
__global__ void k_setup(const float* __restrict__ x, const float* __restrict__ w_in,
    const float* __restrict__ wl, const float* __restrict__ wr,
    const float* __restrict__ iw, const float* __restrict__ ow,
    const float* __restrict__ w1, const float* __restrict__ w2,
    ushort* __restrict__ dst, const int* __restrict__ edst, int* __restrict__ deg){
  if(blockIdx.x >= NCAST){
    int i = (blockIdx.x - NCAST)*256 + threadIdx.x;
    int stride = 512*256;
    for(; i<NEDGE; i+=stride) atomicAdd(&deg[edst[i]], 1);
    return;
  }
  int i = blockIdx.x*256 + threadIdx.x;
  float val;
  if(i < CX)       val = x[i];
  else if(i < CWI) val = w_in[i-CX];
  else if(i < CSW){
    int j = i - CWI;
    int l = j >> 17, r = (j >> 9) & 255, k = j & 511;
    val = (k < 256) ? wl[(l<<16) + (r<<8) + k] : wr[(l<<16) + (r<<8) + (k-256)];
  }
  else if(i < CIW) val = iw[i-CSW];
  else if(i < COW) val = ow[i-CIW];
  else if(i < CW1) val = w1[i-COW];
  else             val = w2[i-CW1];
  dst[i] = f2b(val);
}

__global__ void k_scan(const int* __restrict__ deg, int* __restrict__ offs,
                       float* __restrict__ inv_deg){
  __shared__ int s[1024];
  int t = threadIdx.x;
  int base = t*8;
  int loc[8]; int acc=0;
  #pragma unroll
  for(int j=0;j<8;j++){
    int dv = deg[base+j];
    inv_deg[base+j] = 1.0f/(float)(dv>0?dv:1);
    loc[j]=acc; acc += dv;
  }
  s[t]=acc;
  __syncthreads();
  for(int d=1; d<1024; d<<=1){
    int v = (t>=d)? s[t-d] : 0;
    __syncthreads();
    if(t>=d) s[t]+=v;
    __syncthreads();
  }
  int pre = (t>0)? s[t-1] : 0;
  #pragma unroll
  for(int j=0;j<8;j++) offs[base+j] = pre + loc[j];
  if(t==1023) offs[N_NODES] = s[1023];
}

// ---------------------------------------------------------------------------
// GEMM building blocks (64x64 tile, BK=64)
// ---------------------------------------------------------------------------
#define STAGE_AB(t, buf) do{ \
    int kt_ = (t)*64; \
    _Pragma("unroll") \
    for(int it=0; it<2; ++it){ \
      int c = (wave*2+it)*64 + lane; \
      int row = c >> 3, q = c & 7; \
      int qs = q ^ (row & 7); \
      gload16(A + (size_t)(bm+row)*lda + kt_ + qs*8, (char*)As + (buf)*8192 + (wave*2+it)*1024); \
      gload16(W + (size_t)(bn+row)*K   + kt_ + qs*8, (char*)Bs + (buf)*8192 + (wave*2+it)*1024); \
    } \
  }while(0)

#define MM_COMPUTE(BUFOFF) \
      _Pragma("unroll") \
      for(int kk=0; kk<2; ++kk){ \
        s16x8 af[2], bfr[2]; \
        _Pragma("unroll") \
        for(int mi=0; mi<2; ++mi){ \
          int row = wr*32 + mi*16 + l15; \
          int col = (kk*64 + l4*16) ^ ((row & 7) << 4); \
          af[mi] = *(const s16x8*)((const char*)As + (BUFOFF) + row*128 + col); \
        } \
        _Pragma("unroll") \
        for(int nj=0; nj<2; ++nj){ \
          int row = wc*32 + nj*16 + l15; \
          int col = (kk*64 + l4*16) ^ ((row & 7) << 4); \
          bfr[nj] = *(const s16x8*)((const char*)Bs + (BUFOFF) + row*128 + col); \
        } \
        _Pragma("unroll") \
        for(int mi=0; mi<2; ++mi) \
          _Pragma("unroll") \
          for(int nj=0; nj<2; ++nj) \
            acc[mi][nj] = __builtin_amdgcn_mfma_f32_16x16x32_bf16(af[mi], bfr[nj], acc[mi][nj], 0,0,0); \
      }

// double-buffered loop (standalone GEMMs)
#define MM_LOOP \
  f32x4 acc[2][2] = {}; \
  { const int nt = K >> 6; \
    STAGE_AB(0, 0); \
    asm volatile("s_waitcnt vmcnt(0)" ::: "memory"); \
    __builtin_amdgcn_s_barrier(); \
    int cur = 0; \
    for(int t=0; t<nt; ++t){ \
      if(t+1 < nt) STAGE_AB(t+1, cur^1); \
      MM_COMPUTE(cur*8192) \
      asm volatile("s_waitcnt vmcnt(0)" ::: "memory"); \
      __builtin_amdgcn_s_barrier(); \
      cur ^= 1; \
    } \
  }

// single-buffered loop (merged kernels: minimal LDS union)
#define MM_LOOP_SB \
  f32x4 acc[2][2] = {}; \
  { const int nt = K >> 6; \
    for(int t=0; t<nt; ++t){ \
      __syncthreads(); \
      STAGE_AB(t, 0); \
      asm volatile("s_waitcnt vmcnt(0)" ::: "memory"); \
      __builtin_amdgcn_s_barrier(); \
      MM_COMPUTE(0) \
    } \
  }

// generic GEMM: bf16 resid (ldrb) + bf16 out + optional BN stats
template<bool RELU, bool RESIDB, bool BIAS, bool WBF, bool STATS>
__global__ __launch_bounds__(256) void k_mm(const ushort* __restrict__ A,
    const ushort* __restrict__ W, const float* __restrict__ bias,
    const ushort* __restrict__ residb, ushort* __restrict__ Cb,
    float* __restrict__ gS, float* __restrict__ gQ,
    int M, int Nc, int K, int lda, int ldcb, int ldrb)
{
  __shared__ ushort As[2*64*64];
  __shared__ ushort Bs[2*64*64];
  __shared__ float sredS[64];
  __shared__ float sredQ[64];
  const int tid = threadIdx.x;
  const int lane = tid & 63, wave = tid >> 6;
  const int l15 = lane & 15, l4 = lane >> 4;
  const int bm = blockIdx.y*64, bn = blockIdx.x*64;
  const int wr = wave >> 1, wc = wave & 1;
  MM_LOOP

  float sloc[2] = {0.f,0.f}, qloc[2] = {0.f,0.f};
  #pragma unroll
  for(int mi=0; mi<2; ++mi){
    #pragma unroll
    for(int nj=0; nj<2; ++nj){
      int col = bn + wc*32 + nj*16 + l15;
      float bv = BIAS ? bias[col] : 0.f;
      #pragma unroll
      for(int r=0; r<4; ++r){
        int row = bm + wr*32 + mi*16 + l4*4 + r;
        float v = acc[mi][nj][r] + bv;
        if(RESIDB) v += b2f(residb[(size_t)row*ldrb + col]);
        if(RELU)   v = fmaxf(v, 0.f);
        if(WBF)    Cb[(size_t)row*ldcb + col] = f2b(v);
        if(STATS){ sloc[nj] += v; qloc[nj] += v*v; }
      }
    }
  }
  if(STATS){
    if(tid < 64){ sredS[tid]=0.f; sredQ[tid]=0.f; }
    __syncthreads();
    int c0 = wc*32 + l15;
    atomicAdd(&sredS[c0],    sloc[0]); atomicAdd(&sredQ[c0],    qloc[0]);
    atomicAdd(&sredS[c0+16], sloc[1]); atomicAdd(&sredQ[c0+16], qloc[1]);
    __syncthreads();
    if(tid < 64){
      atomicAdd(&gS[bn+tid], sredS[tid]);
      atomicAdd(&gQ[bn+tid], sredQ[tid]);
    }
  }
}

// ---------------------------------------------------------------------------
// Merged: CSR fill (blocks [0,512)) ∪ in_proj GEMM ([512,1024)), 16KB union
// ---------------------------------------------------------------------------
__global__ __launch_bounds__(256) void k_fill_inproj(const int* __restrict__ src,
    const int* __restrict__ dst, const int* __restrict__ offs,
    int* __restrict__ cursor, int* __restrict__ csr,
    const ushort* __restrict__ xb, const ushort* __restrict__ w_in_b,
    const float* __restrict__ b_in, ushort* __restrict__ hwb)
{
  __shared__ __align__(16) char smem[16384];
  const int tid = threadIdx.x;
  if(blockIdx.x < 512){
    int i = blockIdx.x*256 + tid;
    for(; i<NEDGE; i+=512*256){
      int d = dst[i];
      int p = atomicAdd(&cursor[d], 1);
      csr[offs[d]+p] = src[i];
    }
  } else {
    int idx = blockIdx.x - 512;
    const int lane = tid & 63, wave = tid >> 6;
    const int l15 = lane & 15, l4 = lane >> 4;
    const int bn = (idx & 3)*64, bm = (idx >> 2)*64;
    const int wr = wave >> 1, wc = wave & 1;
    const ushort* A = xb;
    const ushort* W = w_in_b;
    const int K = INC, lda = INC;
    ushort* As = (ushort*)smem;
    ushort* Bs = As + 4096;
    MM_LOOP_SB
    #pragma unroll
    for(int mi=0; mi<2; ++mi){
      #pragma unroll
      for(int nj=0; nj<2; ++nj){
        int col = bn + wc*32 + nj*16 + l15;
        float bv = b_in[col];
        #pragma unroll
        for(int r=0; r<4; ++r){
          int row = bm + wr*32 + mi*16 + l4*4 + r;
          hwb[(size_t)row*512 + 256 + col] = f2b(acc[mi][nj][r] + bv);
        }
      }
    }
  }
}

// ---------------------------------------------------------------------------
// Merged dispatch 1: aggregate (blocks [0,2048)) ∪ QKV GEMM ([2048,3584))
// QKV epilogue writes PACKED per-(graph,head) q/k/vpack[64][1024][32]
// ---------------------------------------------------------------------------
__global__ __launch_bounds__(256) void k_agg_qkv(ushort* __restrict__ hwb,
    const int* __restrict__ offs, const int* __restrict__ csr,
    const float* __restrict__ inv_deg, const ushort* __restrict__ iwb,
    const float* __restrict__ attn_ib, ushort* __restrict__ qpack,
    ushort* __restrict__ kpack, ushort* __restrict__ vpack)
{
  __shared__ __align__(16) char smem[16384];
  const int tid = threadIdx.x;
  const int lane = tid & 63, wave = tid >> 6;
  if(blockIdx.x < 2048){
    // ---- aggregate: one node per wave ----
    int n = blockIdx.x*4 + wave;
    int beg = offs[n], end = offs[n+1];
    f32x4 a0 = {0,0,0,0}, a1 = {0,0,0,0}, a2 = {0,0,0,0}, a3 = {0,0,0,0};
    int i = beg;
    for(; i+4<=end; i+=4){
      int j0=csr[i], j1=csr[i+1], j2=csr[i+2], j3=csr[i+3];
      u16x4 v0 = *(const u16x4*)(hwb + (size_t)j0*512 + 256 + lane*4);
      u16x4 v1 = *(const u16x4*)(hwb + (size_t)j1*512 + 256 + lane*4);
      u16x4 v2 = *(const u16x4*)(hwb + (size_t)j2*512 + 256 + lane*4);
      u16x4 v3 = *(const u16x4*)(hwb + (size_t)j3*512 + 256 + lane*4);
      #pragma unroll
      for(int c=0;c<4;c++){ a0[c]+=b2f(v0[c]); a1[c]+=b2f(v1[c]);
                            a2[c]+=b2f(v2[c]); a3[c]+=b2f(v3[c]); }
    }
    for(; i<end; ++i){
      int j0=csr[i];
      u16x4 v0 = *(const u16x4*)(hwb + (size_t)j0*512 + 256 + lane*4);
      #pragma unroll
      for(int c=0;c<4;c++) a0[c]+=b2f(v0[c]);
    }
    float inv = inv_deg[n];
    u16x4 outv;
    #pragma unroll
    for(int c=0;c<4;c++) outv[c] = f2b((a0[c]+a1[c]+a2[c]+a3[c])*inv);
    *(u16x4*)(hwb + (size_t)n*512 + lane*4) = outv;
  } else {
    // ---- QKV GEMM: A = H (hwb right half, lda=512), W = iwb, Nc=768 ----
    int idx = blockIdx.x - 2048;
    const int bn = (idx % 12)*64, bm = (idx / 12)*64;
    const int l15 = lane & 15, l4 = lane >> 4;
    const int wr = wave >> 1, wc = wave & 1;
    const ushort* A = hwb + 256;
    const ushort* W = iwb;
    const int K = 256, lda = 512;
    ushort* As = (ushort*)smem;
    ushort* Bs = As + 4096;
    MM_LOOP_SB
    const int bgq = bm >> 10;   // 64-row block never crosses a graph boundary
    #pragma unroll
    for(int mi=0; mi<2; ++mi){
      #pragma unroll
      for(int nj=0; nj<2; ++nj){
        int col = bn + wc*32 + nj*16 + l15;
        float bv = attn_ib[col];
        int part = col >> 8;            // 0=Q 1=K 2=V
        int hh = (col >> 5) & 7;
        int dd = col & 31;
        ushort* dstp = (part==0 ? qpack : (part==1 ? kpack : vpack))
                     + (size_t)(bgq*8 + hh)*32768 + dd;
        #pragma unroll
        for(int r=0; r<4; ++r){
          int rig = (bm + wr*32 + mi*16 + l4*4 + r) & 1023;
          dstp[rig*32] = f2b(acc[mi][nj][r] + bv);
        }
      }
    }
  }
}

// ---------------------------------------------------------------------------
// Merged dispatch 2: attention (blocks [0,1024)) ∪ SAGE GEMM ([1024,1536))
// ---------------------------------------------------------------------------
__global__ __launch_bounds__(256) void k_attn_sage(const ushort* __restrict__ qpack,
    const ushort* __restrict__ kpack, const ushort* __restrict__ vpack,
    ushort* __restrict__ attnO, const ushort* __restrict__ hwb,
    const ushort* __restrict__ swb, const float* __restrict__ sage_bl,
    ushort* __restrict__ locB, float* __restrict__ gS, float* __restrict__ gQ)
{
  __shared__ __align__(16) char smem[20992];
  const int tid = threadIdx.x;
  const int lane = tid & 63, wave = tid >> 6;
  const int l15 = lane & 15;
  if(blockIdx.x < 1024){
    // ---- flash attention (3-buf Ks, 2-buf Vt, 1 barrier/tile) ----
    ushort* KsB = (ushort*)smem;          // 3 x 2048 ushorts
    ushort* VtB = (ushort*)smem + 6144;   // 2 x 2048 ushorts
    const int g = lane >> 4;
    int bid = blockIdx.x;
    int h  = bid & 7;
    int bg = (bid >> 3) & 7;
    int qc = bid >> 6;
    const int bgh = bid & 63;
    const int nb = bg*NPG + qc*64 + wave*16;
    const ushort* qp = qpack + (size_t)bgh*32768;
    const ushort* kp = kpack + (size_t)bgh*32768;
    const ushort* vp = vpack + (size_t)bgh*32768;

    const int rho = tid >> 2, qq = tid & 3;
    const int grp = rho >> 5, r32 = rho & 31;
    const int tt = r32 >> 4, wi = r32 & 15;
    const int jperm = grp*32 + (wi >> 2)*8 + tt*4 + (wi & 3);
    const int qs = qq ^ ((rho >> 1) & 3);

    s16x8 qf = *(const s16x8*)(qp + (qc*64 + wave*16 + l15)*32 + g*8);
    {
      const float scale2 = 0.2550370703637335f;   // 1/sqrt(32) * log2(e)
      #pragma unroll
      for(int i=0;i<8;i++) qf[i] = (short)f2b(b2f((ushort)qf[i]) * scale2);
    }
    f32x4 o0 = {0.f,0.f,0.f,0.f}, o1 = {0.f,0.f,0.f,0.f};
    float mrun = -1e30f, lrun = 0.f;

    gload16(kp + (size_t)jperm*32 + qs*8, (char*)KsB + wave*1024);
    s16x8 vcur = *(const s16x8*)(vp + (size_t)lane*32 + wave*8);

    for(int st=0; st<16; ++st){
      int vb = st & 1;
      int kbuf = st % 3;
      ushort* vtb = VtB + vb*2048;
      #pragma unroll
      for(int i=0;i<8;i++){
        int d = wave*8 + i;
        vtb[d*64 + (lane ^ (i<<3))] = (ushort)vcur[i];
      }
      s16x8 vnext = vcur;
      if(st+1 < 16){
        gload16(kp + (size_t)((st+1)*64 + jperm)*32 + qs*8,
                (char*)(KsB + ((st+1)%3)*2048) + wave*1024);
        vnext = *(const s16x8*)(vp + (size_t)((st+1)*64 + lane)*32 + wave*8);
      }
      asm volatile("s_waitcnt lgkmcnt(0)" ::: "memory");
      __builtin_amdgcn_s_barrier();

      const char* ksb = (const char*)(KsB + kbuf*2048);
      f32x4 sc[4];
      __builtin_amdgcn_s_setprio(1);
      #pragma unroll
      for(int q4=0; q4<4; ++q4){
        int r0 = q4*16 + l15;
        s16x8 kf = *(const s16x8*)(ksb + r0*64 + ((g*16) ^ (((r0>>1)&3)<<4)));
        f32x4 z = {0.f,0.f,0.f,0.f};
        sc[q4] = __builtin_amdgcn_mfma_f32_16x16x32_bf16(kf, qf, z, 0,0,0);
      }
      __builtin_amdgcn_s_setprio(0);

      float smax = -1e30f;
      #pragma unroll
      for(int q4=0; q4<4; ++q4)
        #pragma unroll
        for(int r=0; r<4; ++r) smax = fmaxf(smax, sc[q4][r]);
      smax = fmaxf(smax, __shfl_xor(smax, 16));
      smax = fmaxf(smax, __shfl_xor(smax, 32));

      if(!__all((int)(smax <= mrun + 8.0f))){   // defer-max
        float mnew = fmaxf(mrun, smax);
        float alpha = exp2f(mrun - mnew);
        lrun *= alpha;
        #pragma unroll
        for(int r=0;r<4;r++){
          float ar = __shfl(alpha, (lane & 48) | (g*4 + r), 64);
          o0[r] *= ar; o1[r] *= ar;
        }
        mrun = mnew;
      }

      float p[16];
      float ps = 0.f;
      #pragma unroll
      for(int q4=0; q4<4; ++q4)
        #pragma unroll
        for(int r=0; r<4; ++r){
          float pv = exp2f(sc[q4][r] - mrun);
          p[q4*4+r] = pv; ps += pv;
        }
      ps += __shfl_xor(ps, 16);
      ps += __shfl_xor(ps, 32);
      lrun += ps;

      s16x8 pa0, pa1;
      #pragma unroll
      for(int i=0;i<8;i++){ pa0[i] = (short)f2b_trunc(p[i]); pa1[i] = (short)f2b_trunc(p[8+i]); }

      const char* vtc = (const char*)(VtB + vb*2048);
      int colb0 = g*16, colb1 = 64 + g*16;
      int d0 = l15, d1 = l15 + 16;
      s16x8 v00 = *(const s16x8*)(vtc + d0*128 + (colb0 ^ ((d0&7)<<4)));
      s16x8 v01 = *(const s16x8*)(vtc + d1*128 + (colb0 ^ ((d1&7)<<4)));
      s16x8 v10 = *(const s16x8*)(vtc + d0*128 + (colb1 ^ ((d0&7)<<4)));
      s16x8 v11 = *(const s16x8*)(vtc + d1*128 + (colb1 ^ ((d1&7)<<4)));
      __builtin_amdgcn_s_setprio(1);
      o0 = __builtin_amdgcn_mfma_f32_16x16x32_bf16(pa0, v00, o0, 0,0,0);
      o1 = __builtin_amdgcn_mfma_f32_16x16x32_bf16(pa0, v01, o1, 0,0,0);
      o0 = __builtin_amdgcn_mfma_f32_16x16x32_bf16(pa1, v10, o0, 0,0,0);
      o1 = __builtin_amdgcn_mfma_f32_16x16x32_bf16(pa1, v11, o1, 0,0,0);
      __builtin_amdgcn_s_setprio(0);

      vcur = vnext;
    }
    float inv = 1.0f/lrun;
    #pragma unroll
    for(int r=0;r<4;r++){
      int q2 = g*4 + r;
      float ir = __shfl(inv, (lane & 48) | q2, 64);
      size_t nrow = (size_t)(nb + q2)*DIM + h*32;
      attnO[nrow + l15]      = f2b(o0[r]*ir);
      attnO[nrow + 16 + l15] = f2b(o1[r]*ir);
    }
  } else {
    // ---- SAGE GEMM: A=[agg|H] K=512, +bias +H resid (bf16), BN1 stats -> locB ----
    int idx = blockIdx.x - 1024;
    const int bn = (idx & 3)*64, bm = (idx >> 2)*64;
    const int l4 = lane >> 4;
    const int wr = wave >> 1, wc = wave & 1;
    const ushort* A = hwb;
    const ushort* W = swb;
    const int K = 512, lda = 512;
    ushort* As = (ushort*)smem;
    ushort* Bs = As + 4096;
    float* sredS = (float*)(smem + 16384);
    float* sredQ = sredS + 64;
    MM_LOOP_SB

    float sloc[2] = {0.f,0.f}, qloc[2] = {0.f,0.f};
    #pragma unroll
    for(int mi=0; mi<2; ++mi){
      #pragma unroll
      for(int nj=0; nj<2; ++nj){
        int col = bn + wc*32 + nj*16 + l15;
        float bv = sage_bl[col];
        #pragma unroll
        for(int r=0; r<4; ++r){
          int row = bm + wr*32 + mi*16 + l4*4 + r;
          float v = acc[mi][nj][r] + bv + b2f(hwb[(size_t)row*512 + 256 + col]);
          locB[(size_t)row*DIM + col] = f2b(v);
          sloc[nj] += v; qloc[nj] += v*v;
        }
      }
    }
    if(tid < 64){ sredS[tid]=0.f; sredQ[tid]=0.f; }
    __syncthreads();
    int c0 = wc*32 + l15;
    atomicAdd(&sredS[c0],    sloc[0]); atomicAdd(&sredQ[c0],    qloc[0]);
    atomicAdd(&sredS[c0+16], sloc[1]); atomicAdd(&sredQ[c0+16], qloc[1]);
    __syncthreads();
    if(tid < 64){
      atomicAdd(&gS[bn+tid], sredS[tid]);
      atomicAdd(&gQ[bn+tid], sredQ[tid]);
    }
  }
}

// ---------------------------------------------------------------------------
// Vectorized BN applies (u16x4/f32x4). slot: [s1|q1|s2|q2|s3|q3] x 256 floats
// ---------------------------------------------------------------------------
__global__ __launch_bounds__(256) void k_apply12(const ushort* __restrict__ locB,
    const ushort* __restrict__ globB, const float* __restrict__ slot,
    const float* __restrict__ n1w, const float* __restrict__ n1b,
    const float* __restrict__ n2w, const float* __restrict__ n2b,
    ushort* __restrict__ combB){
  int t = blockIdx.x*256 + threadIdx.x;
  int base = t*4;
  int d0 = base & 255;
  u16x4 lv = *(const u16x4*)(locB + base);
  u16x4 gv = *(const u16x4*)(globB + base);
  f32x4 s1 = *(const f32x4*)(slot + d0);
  f32x4 q1 = *(const f32x4*)(slot + 256 + d0);
  f32x4 s2 = *(const f32x4*)(slot + 512 + d0);
  f32x4 q2 = *(const f32x4*)(slot + 768 + d0);
  f32x4 w1v = *(const f32x4*)(n1w + d0);
  f32x4 b1v = *(const f32x4*)(n1b + d0);
  f32x4 w2v = *(const f32x4*)(n2w + d0);
  f32x4 b2v = *(const f32x4*)(n2b + d0);
  const float invn = 1.0f/N_NODES;
  u16x4 outv;
  #pragma unroll
  for(int c=0;c<4;c++){
    float m1 = s1[c]*invn, v1 = q1[c]*invn - m1*m1;
    float m2 = s2[c]*invn, v2 = q2[c]*invn - m2*m2;
    float y1 = (b2f(lv[c])-m1)*rsqrtf(v1+EPS)*w1v[c] + b1v[c];
    float y2 = (b2f(gv[c])-m2)*rsqrtf(v2+EPS)*w2v[c] + b2v[c];
    outv[c] = f2b(y1 + y2);
  }
  *(u16x4*)(combB + base) = outv;
}

// BN3 + outer BN + relu + residual (closed form; vectorized, bf16 state)
__global__ __launch_bounds__(256) void k_apply3o(const ushort* __restrict__ xB,
    const float* __restrict__ slot, const float* __restrict__ n3w,
    const float* __restrict__ bw, const float* __restrict__ bb,
    ushort* __restrict__ hwbR){
  int t = blockIdx.x*256 + threadIdx.x;
  int base = t*4;
  int d0 = base & 255;
  int row = base >> 8;
  u16x4 xv = *(const u16x4*)(xB + base);
  u16x4 hv = *(const u16x4*)(hwbR + (size_t)row*512 + d0);
  f32x4 s3 = *(const f32x4*)(slot + 1024 + d0);
  f32x4 q3 = *(const f32x4*)(slot + 1280 + d0);
  f32x4 wv3 = *(const f32x4*)(n3w + d0);
  f32x4 bwv = *(const f32x4*)(bw + d0);
  f32x4 bbv = *(const f32x4*)(bb + d0);
  const float invn = 1.0f/N_NODES;
  u16x4 outv;
  #pragma unroll
  for(int c=0;c<4;c++){
    float m = s3[c]*invn, var = q3[c]*invn - m*m;
    float rs = rsqrtf(var+EPS);
    float gch = rs*wv3[c];
    float rso = rsqrtf(gch*gch*var + EPS);
    float yo = (b2f(xv[c])-m)*gch*rso*bwv[c] + bbv[c];
    outv[c] = f2b(b2f(hv[c]) + fmaxf(yo, 0.f));
  }
  *(u16x4*)(hwbR + (size_t)row*512 + d0) = outv;
}

// ---------------------------------------------------------------------------
// Pooling (bf16 H) + head
// ---------------------------------------------------------------------------
__global__ void k_pool(const ushort* __restrict__ hwbR, float* __restrict__ pooled){
  int b = blockIdx.x, c = blockIdx.y, d = threadIdx.x;
  int r0 = c*64;
  float s=0.f;
  for(int i=0;i<64;i++) s += b2f(hwbR[(size_t)(b*NPG + r0 + i)*512 + d]);
  atomicAdd(&pooled[b*DIM+d], s*(1.0f/NPG));
}
__global__ void k_out(const float* __restrict__ pooled, const float* __restrict__ w_out,
                      const float* __restrict__ b_out, float* __restrict__ out){
  int t = threadIdx.x;
  if(t >= BGRAPH*OUTD) return;
  int b = t/OUTD, oc = t%OUTD;
  float s = b_out[oc];
  for(int k=0;k<DIM;k++) s += pooled[b*DIM+k]*w_out[oc*DIM+k];
  out[t] = s;
}

// ---------------------------------------------------------------------------
// Orchestration
// ---------------------------------------------------------------------------
extern "C" void kernel_launch(void* const* d_in, const int* in_sizes, int n_in,
                              void* d_out, int out_size, void* d_ws, size_t ws_size,
                              hipStream_t stream) {
  const float* x       = (const float*)d_in[0];
  const int*   edge    = (const int*)d_in[1];
  const float* w_in    = (const float*)d_in[3];
  const float* b_in    = (const float*)d_in[4];
  const float* sage_wl = (const float*)d_in[5];
  const float* sage_bl = (const float*)d_in[6];
  const float* sage_wr = (const float*)d_in[7];
  const float* attn_iw = (const float*)d_in[8];
  const float* attn_ib = (const float*)d_in[9];
  const float* attn_ow = (const float*)d_in[10];
  const float* attn_ob = (const float*)d_in[11];
  const float* n1_w = (const float*)d_in[12];
  const float* n1_b = (const float*)d_in[13];
  const float* n2_w = (const float*)d_in[14];
  const float* n2_b = (const float*)d_in[15];
  const float* n3_w = (const float*)d_in[16];
  const float* n3_b = (const float*)d_in[17];
  const float* mlp_w1 = (const float*)d_in[18];
  const float* mlp_b1 = (const float*)d_in[19];
  const float* mlp_w2 = (const float*)d_in[20];
  const float* mlp_b2 = (const float*)d_in[21];
  const float* bn_w = (const float*)d_in[22];
  const float* bn_b = (const float*)d_in[23];
  const float* w_out = (const float*)d_in[24];
  const float* b_out = (const float*)d_in[25];

  const size_t ND = (size_t)N_NODES*DIM;        // 2,097,152
  ushort* wsb   = (ushort*)d_ws;
  ushort* locB  = wsb;             // [N][256] bf16
  ushort* globB = wsb + ND;        // [N][256] bf16
  ushort* hwb   = wsb + 2*ND;      // [N][512] : [agg | H] bf16
  ushort* qpack = wsb + 4*ND;      // [64][1024][32]
  ushort* kpack = wsb + 5*ND;      // [64][1024][32]
  ushort* vpack = wsb + 6*ND;      // [64][1024][32]
  ushort* attnOb= wsb + 7*ND;      // [N][256]
  ushort* combb = wsb + 8*ND;      // [N][256]
  ushort* hidb  = wsb + 9*ND;      // [N][512]
  ushort* castb = wsb + 11*ND;     // CW2 elems
  ushort* xb     = castb;
  ushort* w_in_b = castb + CX;
  ushort* sageWb = castb + CWI;
  ushort* iw_b   = castb + CSW;
  ushort* ow_b   = castb + CIW;
  ushort* w1_b   = castb + COW;
  ushort* w2_b   = castb + CW1;
  float* mf      = (float*)(castb + CW2);
  float* inv_deg = mf;                       // 8192
  float* bnslots = mf + 8192;                // 3072 (zeroed)
  float* pooled  = bnslots + 3072;           // 2048 (zeroed)
  int* deg    = (int*)(pooled + 2048);       // 8192 (zeroed)
  int* cursor = deg + N_NODES;               // 8192 (zeroed)
  int* offs   = cursor + N_NODES;            // 8193 (+pad)
  int* csr    = offs + N_NODES + 8;

  const int* esrc = edge;
  const int* edst = edge + NEDGE;

  // zero bnslots + pooled + deg + cursor (contiguous)
  hipMemsetAsync(bnslots, 0, (3072+2048)*sizeof(float) + 2*N_NODES*sizeof(int), stream);

  k_setup<<<NCAST+512,256,0,stream>>>(x, w_in, sage_wl, sage_wr, attn_iw,
      attn_ow, mlp_w1, mlp_w2, castb, edst, deg);
  k_scan<<<1,1024,0,stream>>>(deg, offs, inv_deg);

  // CSR fill ∪ in_proj (both ready after scan)
  k_fill_inproj<<<1024,256,0,stream>>>(esrc, edst, offs, cursor, csr,
      xb, w_in_b, b_in, hwb);

  for(int l=0; l<NLAYERS; ++l){
    const ushort* swb = sageWb + (size_t)l*131072;   // [256][512] = [wl|wr]
    const ushort* iwb = iw_b + (size_t)l*196608;
    const ushort* owb = ow_b + (size_t)l*65536;
    const ushort* w1b = w1_b + (size_t)l*131072;
    const ushort* w2b = w2_b + (size_t)l*131072;
    float* slot = bnslots + (size_t)l*1536;

    // D1: aggregate ∪ QKV GEMM (packed q/k/v output)
    k_agg_qkv<<<3584,256,0,stream>>>(hwb, offs, csr, inv_deg, iwb,
        attn_ib + l*3*DIM, qpack, kpack, vpack);

    // D2: attention (packed input) ∪ SAGE GEMM (bf16 H resid, BN1 stats)
    k_attn_sage<<<1536,256,0,stream>>>(qpack, kpack, vpack, attnOb, hwb, swb,
        sage_bl + l*DIM, locB, slot, slot+256);

    // out-proj (+bf16 H resid, BN2 stats) -> globB
    k_mm<false,true,true,true,true><<<dim3(4,128),256,0,stream>>>(
        attnOb, owb, attn_ob + l*DIM, hwb+256, globB, slot+512, slot+768,
        N_NODES, DIM, DIM, DIM, DIM, 512);

    // comb = BN1(loc) + BN2(glob)
    k_apply12<<<2048,256,0,stream>>>(locB, globB, slot,
        n1_w + l*DIM, n1_b + l*DIM, n2_w + l*DIM, n2_b + l*DIM, combb);

    // MLP1: hid = relu(comb@w1^T+b1) -> hidb
    k_mm<true,false,true,true,false><<<dim3(8,128),256,0,stream>>>(
        combb, w1b, mlp_b1 + l*DFF, nullptr, hidb, nullptr, nullptr,
        N_NODES, DFF, DIM, DIM, 512, 256);

    // MLP2: out2 = comb + hid@w2^T + b2 (+BN3 stats) -> globB
    k_mm<false,true,true,true,true><<<dim3(4,128),256,0,stream>>>(
        hidb, w2b, mlp_b2 + l*DIM, combb, globB, slot+1024, slot+1280,
        N_NODES, DIM, 512, 512, DIM, 256);

    // BN3 + outer BN + relu + residual -> hwb right half (bf16 H)
    k_apply3o<<<2048,256,0,stream>>>(globB, slot, n3_w + l*DIM,
        bn_w + l*DIM, bn_b + l*DIM, hwb+256);
  }

  k_pool<<<dim3(BGRAPH, NPG/64),256,0,stream>>>(hwb+256, pooled);
  k_out<<<1,512,0,stream>>>(pooled, w_out, b_out, (float*)d_out);
}

// Round 18
// 257.204 us; speedup vs baseline: 1.0365x; 1.0077x over previous
//
#include <hip/hip_runtime.h>
#include <hip/hip_bf16.h>

#define N_NODES 8192
#define BGRAPH 8
#define NPG 1024
#define DIM 256
#define NH 8
#define DHEAD 32
#define NLAYERS 2
#define INC 128
#define OUTD 64
#define NEDGE 262144
#define DFF 512
#define EPS 1e-5f

typedef __attribute__((ext_vector_type(4))) float f32x4;
typedef __attribute__((ext_vector_type(8))) short s16x8;
typedef __attribute__((ext_vector_type(4))) ushort u16x4;

__device__ __forceinline__ float b2f(ushort u){
  unsigned v = ((unsigned)u) << 16;
  return __builtin_bit_cast(float, v);
}
__device__ __forceinline__ ushort f2b(float f){
  unsigned u = __builtin_bit_cast(unsigned, f);
  u += 0x7fffu + ((u >> 16) & 1u);
  return (ushort)(u >> 16);
}
__device__ __forceinline__ ushort f2b_trunc(float f){
  return (ushort)(__builtin_bit_cast(unsigned, f) >> 16);
}
__device__ __forceinline__ float max3f(float a, float b, float c){
  return fmaxf(fmaxf(a,b),c);
}
// async global->LDS, 16B per lane; lds base must be wave-uniform (HW adds lane*16)
__device__ __forceinline__ void gload16(const void* g, void* l){
  __builtin_amdgcn_global_load_lds(
    (const __attribute__((address_space(1))) void*)g,
    (__attribute__((address_space(3))) void*)l,
    16, 0, 0);
}

// ---------------------------------------------------------------------------
// Setup: cast x/weights -> bf16 (sage weights [wl|wr] along K) + degree count
// ---------------------------------------------------------------------------
#define CX  1048576
#define CWI (CX+32768)
#define CSW (CWI+262144)
#define CIW (CSW+393216)
#define COW (CIW+131072)
#define CW1 (COW+262144)
#define CW2 (CW1+262144)   // total 2392064
#define NCAST (CW2/256)
__global__ void k_setup(const float* __restrict__ x, const float* __restrict__ w_in,
    const float* __restrict__ wl, const float* __restrict__ wr,
    const float* __restrict__ iw, const float* __restrict__ ow,
    const float* __restrict__ w1, const float* __restrict__ w2,
    ushort* __restrict__ dst, const int* __restrict__ edst, int* __restrict__ deg){
  if(blockIdx.x >= NCAST){
    int i = (blockIdx.x - NCAST)*256 + threadIdx.x;
    int stride = 512*256;
    for(; i<NEDGE; i+=stride) atomicAdd(&deg[edst[i]], 1);
    return;
  }
  int i = blockIdx.x*256 + threadIdx.x;
  float val;
  if(i < CX)       val = x[i];
  else if(i < CWI) val = w_in[i-CX];
  else if(i < CSW){
    int j = i - CWI;
    int l = j >> 17, r = (j >> 9) & 255, k = j & 511;
    val = (k < 256) ? wl[(l<<16) + (r<<8) + k] : wr[(l<<16) + (r<<8) + (k-256)];
  }
  else if(i < CIW) val = iw[i-CSW];
  else if(i < COW) val = ow[i-CIW];
  else if(i < CW1) val = w1[i-COW];
  else             val = w2[i-CW1];
  dst[i] = f2b(val);
}

__global__ void k_scan(const int* __restrict__ deg, int* __restrict__ offs,
                       float* __restrict__ inv_deg){
  __shared__ int s[1024];
  int t = threadIdx.x;
  int base = t*8;
  int loc[8]; int acc=0;
  #pragma unroll
  for(int j=0;j<8;j++){
    int dv = deg[base+j];
    inv_deg[base+j] = 1.0f/(float)(dv>0?dv:1);
    loc[j]=acc; acc += dv;
  }
  s[t]=acc;
  __syncthreads();
  for(int d=1; d<1024; d<<=1){
    int v = (t>=d)? s[t-d] : 0;
    __syncthreads();
    if(t>=d) s[t]+=v;
    __syncthreads();
  }
  int pre = (t>0)? s[t-1] : 0;
  #pragma unroll
  for(int j=0;j<8;j++) offs[base+j] = pre + loc[j];
  if(t==1023) offs[N_NODES] = s[1023];
}

// ---------------------------------------------------------------------------
// GEMM building blocks (64x64 tile, BK=64)
// ---------------------------------------------------------------------------
#define STAGE_AB(t, buf) do{ \
    int kt_ = (t)*64; \
    _Pragma("unroll") \
    for(int it=0; it<2; ++it){ \
      int c = (wave*2+it)*64 + lane; \
      int row = c >> 3, q = c & 7; \
      int qs = q ^ (row & 7); \
      gload16(A + (size_t)(bm+row)*lda + kt_ + qs*8, (char*)As + (buf)*8192 + (wave*2+it)*1024); \
      gload16(W + (size_t)(bn+row)*K   + kt_ + qs*8, (char*)Bs + (buf)*8192 + (wave*2+it)*1024); \
    } \
  }while(0)

#define MM_COMPUTE(BUFOFF) \
      _Pragma("unroll") \
      for(int kk=0; kk<2; ++kk){ \
        s16x8 af[2], bfr[2]; \
        _Pragma("unroll") \
        for(int mi=0; mi<2; ++mi){ \
          int row = wr*32 + mi*16 + l15; \
          int col = (kk*64 + l4*16) ^ ((row & 7) << 4); \
          af[mi] = *(const s16x8*)((const char*)As + (BUFOFF) + row*128 + col); \
        } \
        _Pragma("unroll") \
        for(int nj=0; nj<2; ++nj){ \
          int row = wc*32 + nj*16 + l15; \
          int col = (kk*64 + l4*16) ^ ((row & 7) << 4); \
          bfr[nj] = *(const s16x8*)((const char*)Bs + (BUFOFF) + row*128 + col); \
        } \
        _Pragma("unroll") \
        for(int mi=0; mi<2; ++mi) \
          _Pragma("unroll") \
          for(int nj=0; nj<2; ++nj) \
            acc[mi][nj] = __builtin_amdgcn_mfma_f32_16x16x32_bf16(af[mi], bfr[nj], acc[mi][nj], 0,0,0); \
      }

// double-buffered loop (standalone GEMMs)
#define MM_LOOP \
  f32x4 acc[2][2] = {}; \
  { const int nt = K >> 6; \
    STAGE_AB(0, 0); \
    asm volatile("s_waitcnt vmcnt(0)" ::: "memory"); \
    __builtin_amdgcn_s_barrier(); \
    int cur = 0; \
    for(int t=0; t<nt; ++t){ \
      if(t+1 < nt) STAGE_AB(t+1, cur^1); \
      MM_COMPUTE(cur*8192) \
      asm volatile("s_waitcnt vmcnt(0)" ::: "memory"); \
      __builtin_amdgcn_s_barrier(); \
      cur ^= 1; \
    } \
  }

// single-buffered loop (merged kernels: minimal LDS union)
#define MM_LOOP_SB \
  f32x4 acc[2][2] = {}; \
  { const int nt = K >> 6; \
    for(int t=0; t<nt; ++t){ \
      __syncthreads(); \
      STAGE_AB(t, 0); \
      asm volatile("s_waitcnt vmcnt(0)" ::: "memory"); \
      __builtin_amdgcn_s_barrier(); \
      MM_COMPUTE(0) \
    } \
  }

// generic GEMM: bf16 resid (ldrb) + bf16 out + optional BN stats
template<bool RELU, bool RESIDB, bool BIAS, bool WBF, bool STATS>
__global__ __launch_bounds__(256) void k_mm(const ushort* __restrict__ A,
    const ushort* __restrict__ W, const float* __restrict__ bias,
    const ushort* __restrict__ residb, ushort* __restrict__ Cb,
    float* __restrict__ gS, float* __restrict__ gQ,
    int M, int Nc, int K, int lda, int ldcb, int ldrb)
{
  __shared__ ushort As[2*64*64];
  __shared__ ushort Bs[2*64*64];
  __shared__ float sredS[64];
  __shared__ float sredQ[64];
  const int tid = threadIdx.x;
  const int lane = tid & 63, wave = tid >> 6;
  const int l15 = lane & 15, l4 = lane >> 4;
  const int bm = blockIdx.y*64, bn = blockIdx.x*64;
  const int wr = wave >> 1, wc = wave & 1;
  MM_LOOP

  float sloc[2] = {0.f,0.f}, qloc[2] = {0.f,0.f};
  #pragma unroll
  for(int mi=0; mi<2; ++mi){
    #pragma unroll
    for(int nj=0; nj<2; ++nj){
      int col = bn + wc*32 + nj*16 + l15;
      float bv = BIAS ? bias[col] : 0.f;
      #pragma unroll
      for(int r=0; r<4; ++r){
        int row = bm + wr*32 + mi*16 + l4*4 + r;
        float v = acc[mi][nj][r] + bv;
        if(RESIDB) v += b2f(residb[(size_t)row*ldrb + col]);
        if(RELU)   v = fmaxf(v, 0.f);
        if(WBF)    Cb[(size_t)row*ldcb + col] = f2b(v);
        if(STATS){ sloc[nj] += v; qloc[nj] += v*v; }
      }
    }
  }
  if(STATS){
    if(tid < 64){ sredS[tid]=0.f; sredQ[tid]=0.f; }
    __syncthreads();
    int c0 = wc*32 + l15;
    atomicAdd(&sredS[c0],    sloc[0]); atomicAdd(&sredQ[c0],    qloc[0]);
    atomicAdd(&sredS[c0+16], sloc[1]); atomicAdd(&sredQ[c0+16], qloc[1]);
    __syncthreads();
    if(tid < 64){
      atomicAdd(&gS[bn+tid], sredS[tid]);
      atomicAdd(&gQ[bn+tid], sredQ[tid]);
    }
  }
}

// ---------------------------------------------------------------------------
// Merged: CSR fill (blocks [0,512)) ∪ in_proj GEMM ([512,1024)), 16KB union
// ---------------------------------------------------------------------------
__global__ __launch_bounds__(256) void k_fill_inproj(const int* __restrict__ src,
    const int* __restrict__ dst, const int* __restrict__ offs,
    int* __restrict__ cursor, int* __restrict__ csr,
    const ushort* __restrict__ xb, const ushort* __restrict__ w_in_b,
    const float* __restrict__ b_in, ushort* __restrict__ hwb)
{
  __shared__ __align__(16) char smem[16384];
  const int tid = threadIdx.x;
  if(blockIdx.x < 512){
    int i = blockIdx.x*256 + tid;
    for(; i<NEDGE; i+=512*256){
      int d = dst[i];
      int p = atomicAdd(&cursor[d], 1);
      csr[offs[d]+p] = src[i];
    }
  } else {
    int idx = blockIdx.x - 512;
    const int lane = tid & 63, wave = tid >> 6;
    const int l15 = lane & 15, l4 = lane >> 4;
    const int bn = (idx & 3)*64, bm = (idx >> 2)*64;
    const int wr = wave >> 1, wc = wave & 1;
    const ushort* A = xb;
    const ushort* W = w_in_b;
    const int K = INC, lda = INC;
    ushort* As = (ushort*)smem;
    ushort* Bs = As + 4096;
    MM_LOOP_SB
    #pragma unroll
    for(int mi=0; mi<2; ++mi){
      #pragma unroll
      for(int nj=0; nj<2; ++nj){
        int col = bn + wc*32 + nj*16 + l15;
        float bv = b_in[col];
        #pragma unroll
        for(int r=0; r<4; ++r){
          int row = bm + wr*32 + mi*16 + l4*4 + r;
          hwb[(size_t)row*512 + 256 + col] = f2b(acc[mi][nj][r] + bv);
        }
      }
    }
  }
}

// ---------------------------------------------------------------------------
// Merged dispatch 1: aggregate (blocks [0,2048)) ∪ QKV GEMM ([2048,3584))
// QKV epilogue writes PACKED per-(graph,head) q/k/vpack[64][1024][32]
// ---------------------------------------------------------------------------
__global__ __launch_bounds__(256) void k_agg_qkv(ushort* __restrict__ hwb,
    const int* __restrict__ offs, const int* __restrict__ csr,
    const float* __restrict__ inv_deg, const ushort* __restrict__ iwb,
    const float* __restrict__ attn_ib, ushort* __restrict__ qpack,
    ushort* __restrict__ kpack, ushort* __restrict__ vpack)
{
  __shared__ __align__(16) char smem[16384];
  const int tid = threadIdx.x;
  const int lane = tid & 63, wave = tid >> 6;
  if(blockIdx.x < 2048){
    // ---- aggregate: one node per wave ----
    int n = blockIdx.x*4 + wave;
    int beg = offs[n], end = offs[n+1];
    f32x4 a0 = {0,0,0,0}, a1 = {0,0,0,0}, a2 = {0,0,0,0}, a3 = {0,0,0,0};
    int i = beg;
    for(; i+4<=end; i+=4){
      int j0=csr[i], j1=csr[i+1], j2=csr[i+2], j3=csr[i+3];
      u16x4 v0 = *(const u16x4*)(hwb + (size_t)j0*512 + 256 + lane*4);
      u16x4 v1 = *(const u16x4*)(hwb + (size_t)j1*512 + 256 + lane*4);
      u16x4 v2 = *(const u16x4*)(hwb + (size_t)j2*512 + 256 + lane*4);
      u16x4 v3 = *(const u16x4*)(hwb + (size_t)j3*512 + 256 + lane*4);
      #pragma unroll
      for(int c=0;c<4;c++){ a0[c]+=b2f(v0[c]); a1[c]+=b2f(v1[c]);
                            a2[c]+=b2f(v2[c]); a3[c]+=b2f(v3[c]); }
    }
    for(; i<end; ++i){
      int j0=csr[i];
      u16x4 v0 = *(const u16x4*)(hwb + (size_t)j0*512 + 256 + lane*4);
      #pragma unroll
      for(int c=0;c<4;c++) a0[c]+=b2f(v0[c]);
    }
    float inv = inv_deg[n];
    u16x4 outv;
    #pragma unroll
    for(int c=0;c<4;c++) outv[c] = f2b((a0[c]+a1[c]+a2[c]+a3[c])*inv);
    *(u16x4*)(hwb + (size_t)n*512 + lane*4) = outv;
  } else {
    // ---- QKV GEMM: A = H (hwb right half, lda=512), W = iwb, Nc=768 ----
    int idx = blockIdx.x - 2048;
    const int bn = (idx % 12)*64, bm = (idx / 12)*64;
    const int l15 = lane & 15, l4 = lane >> 4;
    const int wr = wave >> 1, wc = wave & 1;
    const ushort* A = hwb + 256;
    const ushort* W = iwb;
    const int K = 256, lda = 512;
    ushort* As = (ushort*)smem;
    ushort* Bs = As + 4096;
    MM_LOOP_SB
    const int bgq = bm >> 10;   // 64-row block never crosses a graph boundary
    #pragma unroll
    for(int mi=0; mi<2; ++mi){
      #pragma unroll
      for(int nj=0; nj<2; ++nj){
        int col = bn + wc*32 + nj*16 + l15;
        float bv = attn_ib[col];
        int part = col >> 8;            // 0=Q 1=K 2=V
        int hh = (col >> 5) & 7;
        int dd = col & 31;
        ushort* dstp = (part==0 ? qpack : (part==1 ? kpack : vpack))
                     + (size_t)(bgq*8 + hh)*32768 + dd;
        #pragma unroll
        for(int r=0; r<4; ++r){
          int rig = (bm + wr*32 + mi*16 + l4*4 + r) & 1023;
          dstp[rig*32] = f2b(acc[mi][nj][r] + bv);
        }
      }
    }
  }
}

// ---------------------------------------------------------------------------
// Merged dispatch 2: attention (blocks [0,1024)) ∪ SAGE GEMM ([1024,1536))
// Attention softmax: row-sum via MFMA ones-column (denominator in-lane,
// no shuffles), max reduction via v_max3.
// ---------------------------------------------------------------------------
__global__ __launch_bounds__(256) void k_attn_sage(const ushort* __restrict__ qpack,
    const ushort* __restrict__ kpack, const ushort* __restrict__ vpack,
    ushort* __restrict__ attnO, const ushort* __restrict__ hwb,
    const ushort* __restrict__ swb, const float* __restrict__ sage_bl,
    ushort* __restrict__ locB, float* __restrict__ gS, float* __restrict__ gQ)
{
  __shared__ __align__(16) char smem[20992];
  const int tid = threadIdx.x;
  const int lane = tid & 63, wave = tid >> 6;
  const int l15 = lane & 15;
  if(blockIdx.x < 1024){
    // ---- flash attention (3-buf Ks, 2-buf Vt, 1 barrier/tile) ----
    ushort* KsB = (ushort*)smem;          // 3 x 2048 ushorts
    ushort* VtB = (ushort*)smem + 6144;   // 2 x 2048 ushorts
    const int g = lane >> 4;
    int bid = blockIdx.x;
    int h  = bid & 7;
    int bg = (bid >> 3) & 7;
    int qc = bid >> 6;
    const int bgh = bid & 63;
    const int nb = bg*NPG + qc*64 + wave*16;
    const ushort* qp = qpack + (size_t)bgh*32768;
    const ushort* kp = kpack + (size_t)bgh*32768;
    const ushort* vp = vpack + (size_t)bgh*32768;

    const int rho = tid >> 2, qq = tid & 3;
    const int grp = rho >> 5, r32 = rho & 31;
    const int tt = r32 >> 4, wi = r32 & 15;
    const int jperm = grp*32 + (wi >> 2)*8 + tt*4 + (wi & 3);
    const int qs = qq ^ ((rho >> 1) & 3);

    s16x8 qf = *(const s16x8*)(qp + (qc*64 + wave*16 + l15)*32 + g*8);
    {
      const float scale2 = 0.2550370703637335f;   // 1/sqrt(32) * log2(e)
      #pragma unroll
      for(int i=0;i<8;i++) qf[i] = (short)f2b(b2f((ushort)qf[i]) * scale2);
    }
    s16x8 onesf;
    #pragma unroll
    for(int i=0;i<8;i++) onesf[i] = (short)0x3F80;   // bf16 1.0

    f32x4 o0 = {0.f,0.f,0.f,0.f}, o1 = {0.f,0.f,0.f,0.f};
    f32x4 osum = {0.f,0.f,0.f,0.f};   // row-sums, same row layout as o0/o1
    float mrun = -1e30f;

    gload16(kp + (size_t)jperm*32 + qs*8, (char*)KsB + wave*1024);
    s16x8 vcur = *(const s16x8*)(vp + (size_t)lane*32 + wave*8);

    for(int st=0; st<16; ++st){
      int vb = st & 1;
      int kbuf = st % 3;
      ushort* vtb = VtB + vb*2048;
      #pragma unroll
      for(int i=0;i<8;i++){
        int d = wave*8 + i;
        vtb[d*64 + (lane ^ (i<<3))] = (ushort)vcur[i];
      }
      s16x8 vnext = vcur;
      if(st+1 < 16){
        gload16(kp + (size_t)((st+1)*64 + jperm)*32 + qs*8,
                (char*)(KsB + ((st+1)%3)*2048) + wave*1024);
        vnext = *(const s16x8*)(vp + (size_t)((st+1)*64 + lane)*32 + wave*8);
      }
      asm volatile("s_waitcnt lgkmcnt(0)" ::: "memory");
      __builtin_amdgcn_s_barrier();

      const char* ksb = (const char*)(KsB + kbuf*2048);
      f32x4 sc[4];
      __builtin_amdgcn_s_setprio(1);
      #pragma unroll
      for(int q4=0; q4<4; ++q4){
        int r0 = q4*16 + l15;
        s16x8 kf = *(const s16x8*)(ksb + r0*64 + ((g*16) ^ (((r0>>1)&3)<<4)));
        f32x4 z = {0.f,0.f,0.f,0.f};
        sc[q4] = __builtin_amdgcn_mfma_f32_16x16x32_bf16(kf, qf, z, 0,0,0);
      }
      __builtin_amdgcn_s_setprio(0);

      // max over 16 scores via max3 chain (8 ops)
      float smax = fmaxf(sc[0][0], sc[0][1]);
      smax = max3f(smax, sc[0][2], sc[0][3]);
      smax = max3f(smax, sc[1][0], sc[1][1]);
      smax = max3f(smax, sc[1][2], sc[1][3]);
      smax = max3f(smax, sc[2][0], sc[2][1]);
      smax = max3f(smax, sc[2][2], sc[2][3]);
      smax = max3f(smax, sc[3][0], sc[3][1]);
      smax = max3f(smax, sc[3][2], sc[3][3]);
      smax = fmaxf(smax, __shfl_xor(smax, 16));
      smax = fmaxf(smax, __shfl_xor(smax, 32));

      if(!__all((int)(smax <= mrun + 8.0f))){   // defer-max
        float mnew = fmaxf(mrun, smax);
        float alpha = exp2f(mrun - mnew);
        #pragma unroll
        for(int r=0;r<4;r++){
          float ar = __shfl(alpha, (lane & 48) | (g*4 + r), 64);
          o0[r] *= ar; o1[r] *= ar; osum[r] *= ar;
        }
        mrun = mnew;
      }

      s16x8 pa0, pa1;
      #pragma unroll
      for(int q4=0; q4<2; ++q4)
        #pragma unroll
        for(int r=0; r<4; ++r)
          pa0[q4*4+r] = (short)f2b_trunc(exp2f(sc[q4][r] - mrun));
      #pragma unroll
      for(int q4=2; q4<4; ++q4)
        #pragma unroll
        for(int r=0; r<4; ++r)
          pa1[(q4-2)*4+r] = (short)f2b_trunc(exp2f(sc[q4][r] - mrun));

      const char* vtc = (const char*)(VtB + vb*2048);
      int colb0 = g*16, colb1 = 64 + g*16;
      int d0 = l15, d1 = l15 + 16;
      s16x8 v00 = *(const s16x8*)(vtc + d0*128 + (colb0 ^ ((d0&7)<<4)));
      s16x8 v01 = *(const s16x8*)(vtc + d1*128 + (colb0 ^ ((d1&7)<<4)));
      s16x8 v10 = *(const s16x8*)(vtc + d0*128 + (colb1 ^ ((d0&7)<<4)));
      s16x8 v11 = *(const s16x8*)(vtc + d1*128 + (colb1 ^ ((d1&7)<<4)));
      __builtin_amdgcn_s_setprio(1);
      o0 = __builtin_amdgcn_mfma_f32_16x16x32_bf16(pa0, v00, o0, 0,0,0);
      o1 = __builtin_amdgcn_mfma_f32_16x16x32_bf16(pa0, v01, o1, 0,0,0);
      o0 = __builtin_amdgcn_mfma_f32_16x16x32_bf16(pa1, v10, o0, 0,0,0);
      o1 = __builtin_amdgcn_mfma_f32_16x16x32_bf16(pa1, v11, o1, 0,0,0);
      osum = __builtin_amdgcn_mfma_f32_16x16x32_bf16(pa0, onesf, osum, 0,0,0);
      osum = __builtin_amdgcn_mfma_f32_16x16x32_bf16(pa1, onesf, osum, 0,0,0);
      __builtin_amdgcn_s_setprio(0);

      vcur = vnext;
    }
    // denominator in-lane: osum[r] = rowsum for row q2=g*4+r (all cols equal)
    #pragma unroll
    for(int r=0;r<4;r++){
      int q2 = g*4 + r;
      float ir = 1.0f/osum[r];
      size_t nrow = (size_t)(nb + q2)*DIM + h*32;
      attnO[nrow + l15]      = f2b(o0[r]*ir);
      attnO[nrow + 16 + l15] = f2b(o1[r]*ir);
    }
  } else {
    // ---- SAGE GEMM: A=[agg|H] K=512, +bias +H resid (bf16), BN1 stats -> locB ----
    int idx = blockIdx.x - 1024;
    const int bn = (idx & 3)*64, bm = (idx >> 2)*64;
    const int l4 = lane >> 4;
    const int wr = wave >> 1, wc = wave & 1;
    const ushort* A = hwb;
    const ushort* W = swb;
    const int K = 512, lda = 512;
    ushort* As = (ushort*)smem;
    ushort* Bs = As + 4096;
    float* sredS = (float*)(smem + 16384);
    float* sredQ = sredS + 64;
    MM_LOOP_SB

    float sloc[2] = {0.f,0.f}, qloc[2] = {0.f,0.f};
    #pragma unroll
    for(int mi=0; mi<2; ++mi){
      #pragma unroll
      for(int nj=0; nj<2; ++nj){
        int col = bn + wc*32 + nj*16 + l15;
        float bv = sage_bl[col];
        #pragma unroll
        for(int r=0; r<4; ++r){
          int row = bm + wr*32 + mi*16 + l4*4 + r;
          float v = acc[mi][nj][r] + bv + b2f(hwb[(size_t)row*512 + 256 + col]);
          locB[(size_t)row*DIM + col] = f2b(v);
          sloc[nj] += v; qloc[nj] += v*v;
        }
      }
    }
    if(tid < 64){ sredS[tid]=0.f; sredQ[tid]=0.f; }
    __syncthreads();
    int c0 = wc*32 + l15;
    atomicAdd(&sredS[c0],    sloc[0]); atomicAdd(&sredQ[c0],    qloc[0]);
    atomicAdd(&sredS[c0+16], sloc[1]); atomicAdd(&sredQ[c0+16], qloc[1]);
    __syncthreads();
    if(tid < 64){
      atomicAdd(&gS[bn+tid], sredS[tid]);
      atomicAdd(&gQ[bn+tid], sredQ[tid]);
    }
  }
}

// ---------------------------------------------------------------------------
// Vectorized BN applies (u16x4/f32x4). slot: [s1|q1|s2|q2|s3|q3] x 256 floats
// ---------------------------------------------------------------------------
__global__ __launch_bounds__(256) void k_apply12(const ushort* __restrict__ locB,
    const ushort* __restrict__ globB, const float* __restrict__ slot,
    const float* __restrict__ n1w, const float* __restrict__ n1b,
    const float* __restrict__ n2w, const float* __restrict__ n2b,
    ushort* __restrict__ combB){
  int t = blockIdx.x*256 + threadIdx.x;
  int base = t*4;
  int d0 = base & 255;
  u16x4 lv = *(const u16x4*)(locB + base);
  u16x4 gv = *(const u16x4*)(globB + base);
  f32x4 s1 = *(const f32x4*)(slot + d0);
  f32x4 q1 = *(const f32x4*)(slot + 256 + d0);
  f32x4 s2 = *(const f32x4*)(slot + 512 + d0);
  f32x4 q2 = *(const f32x4*)(slot + 768 + d0);
  f32x4 w1v = *(const f32x4*)(n1w + d0);
  f32x4 b1v = *(const f32x4*)(n1b + d0);
  f32x4 w2v = *(const f32x4*)(n2w + d0);
  f32x4 b2v = *(const f32x4*)(n2b + d0);
  const float invn = 1.0f/N_NODES;
  u16x4 outv;
  #pragma unroll
  for(int c=0;c<4;c++){
    float m1 = s1[c]*invn, v1 = q1[c]*invn - m1*m1;
    float m2 = s2[c]*invn, v2 = q2[c]*invn - m2*m2;
    float y1 = (b2f(lv[c])-m1)*rsqrtf(v1+EPS)*w1v[c] + b1v[c];
    float y2 = (b2f(gv[c])-m2)*rsqrtf(v2+EPS)*w2v[c] + b2v[c];
    outv[c] = f2b(y1 + y2);
  }
  *(u16x4*)(combB + base) = outv;
}

// BN3 + outer BN + relu + residual (closed form; vectorized, bf16 state)
__global__ __launch_bounds__(256) void k_apply3o(const ushort* __restrict__ xB,
    const float* __restrict__ slot, const float* __restrict__ n3w,
    const float* __restrict__ bw, const float* __restrict__ bb,
    ushort* __restrict__ hwbR){
  int t = blockIdx.x*256 + threadIdx.x;
  int base = t*4;
  int d0 = base & 255;
  int row = base >> 8;
  u16x4 xv = *(const u16x4*)(xB + base);
  u16x4 hv = *(const u16x4*)(hwbR + (size_t)row*512 + d0);
  f32x4 s3 = *(const f32x4*)(slot + 1024 + d0);
  f32x4 q3 = *(const f32x4*)(slot + 1280 + d0);
  f32x4 wv3 = *(const f32x4*)(n3w + d0);
  f32x4 bwv = *(const f32x4*)(bw + d0);
  f32x4 bbv = *(const f32x4*)(bb + d0);
  const float invn = 1.0f/N_NODES;
  u16x4 outv;
  #pragma unroll
  for(int c=0;c<4;c++){
    float m = s3[c]*invn, var = q3[c]*invn - m*m;
    float rs = rsqrtf(var+EPS);
    float gch = rs*wv3[c];
    float rso = rsqrtf(gch*gch*var + EPS);
    float yo = (b2f(xv[c])-m)*gch*rso*bwv[c] + bbv[c];
    outv[c] = f2b(b2f(hv[c]) + fmaxf(yo, 0.f));
  }
  *(u16x4*)(hwbR + (size_t)row*512 + d0) = outv;
}

// ---------------------------------------------------------------------------
// Pooling (bf16 H) + head
// ---------------------------------------------------------------------------
__global__ void k_pool(const ushort* __restrict__ hwbR, float* __restrict__ pooled){
  int b = blockIdx.x, c = blockIdx.y, d = threadIdx.x;
  int r0 = c*64;
  float s=0.f;
  for(int i=0;i<64;i++) s += b2f(hwbR[(size_t)(b*NPG + r0 + i)*512 + d]);
  atomicAdd(&pooled[b*DIM+d], s*(1.0f/NPG));
}
__global__ void k_out(const float* __restrict__ pooled, const float* __restrict__ w_out,
                      const float* __restrict__ b_out, float* __restrict__ out){
  int t = threadIdx.x;
  if(t >= BGRAPH*OUTD) return;
  int b = t/OUTD, oc = t%OUTD;
  float s = b_out[oc];
  for(int k=0;k<DIM;k++) s += pooled[b*DIM+k]*w_out[oc*DIM+k];
  out[t] = s;
}

// ---------------------------------------------------------------------------
// Orchestration
// ---------------------------------------------------------------------------
extern "C" void kernel_launch(void* const* d_in, const int* in_sizes, int n_in,
                              void* d_out, int out_size, void* d_ws, size_t ws_size,
                              hipStream_t stream) {
  const float* x       = (const float*)d_in[0];
  const int*   edge    = (const int*)d_in[1];
  const float* w_in    = (const float*)d_in[3];
  const float* b_in    = (const float*)d_in[4];
  const float* sage_wl = (const float*)d_in[5];
  const float* sage_bl = (const float*)d_in[6];
  const float* sage_wr = (const float*)d_in[7];
  const float* attn_iw = (const float*)d_in[8];
  const float* attn_ib = (const float*)d_in[9];
  const float* attn_ow = (const float*)d_in[10];
  const float* attn_ob = (const float*)d_in[11];
  const float* n1_w = (const float*)d_in[12];
  const float* n1_b = (const float*)d_in[13];
  const float* n2_w = (const float*)d_in[14];
  const float* n2_b = (const float*)d_in[15];
  const float* n3_w = (const float*)d_in[16];
  const float* n3_b = (const float*)d_in[17];
  const float* mlp_w1 = (const float*)d_in[18];
  const float* mlp_b1 = (const float*)d_in[19];
  const float* mlp_w2 = (const float*)d_in[20];
  const float* mlp_b2 = (const float*)d_in[21];
  const float* bn_w = (const float*)d_in[22];
  const float* bn_b = (const float*)d_in[23];
  const float* w_out = (const float*)d_in[24];
  const float* b_out = (const float*)d_in[25];

  const size_t ND = (size_t)N_NODES*DIM;        // 2,097,152
  ushort* wsb   = (ushort*)d_ws;
  ushort* locB  = wsb;             // [N][256] bf16
  ushort* globB = wsb + ND;        // [N][256] bf16
  ushort* hwb   = wsb + 2*ND;      // [N][512] : [agg | H] bf16
  ushort* qpack = wsb + 4*ND;      // [64][1024][32]
  ushort* kpack = wsb + 5*ND;      // [64][1024][32]
  ushort* vpack = wsb + 6*ND;      // [64][1024][32]
  ushort* attnOb= wsb + 7*ND;      // [N][256]
  ushort* combb = wsb + 8*ND;      // [N][256]
  ushort* hidb  = wsb + 9*ND;      // [N][512]
  ushort* castb = wsb + 11*ND;     // CW2 elems
  ushort* xb     = castb;
  ushort* w_in_b = castb + CX;
  ushort* sageWb = castb + CWI;
  ushort* iw_b   = castb + CSW;
  ushort* ow_b   = castb + CIW;
  ushort* w1_b   = castb + COW;
  ushort* w2_b   = castb + CW1;
  float* mf      = (float*)(castb + CW2);
  float* inv_deg = mf;                       // 8192
  float* bnslots = mf + 8192;                // 3072 (zeroed)
  float* pooled  = bnslots + 3072;           // 2048 (zeroed)
  int* deg    = (int*)(pooled + 2048);       // 8192 (zeroed)
  int* cursor = deg + N_NODES;               // 8192 (zeroed)
  int* offs   = cursor + N_NODES;            // 8193 (+pad)
  int* csr    = offs + N_NODES + 8;

  const int* esrc = edge;
  const int* edst = edge + NEDGE;

  // zero bnslots + pooled + deg + cursor (contiguous)
  hipMemsetAsync(bnslots, 0, (3072+2048)*sizeof(float) + 2*N_NODES*sizeof(int), stream);

  k_setup<<<NCAST+512,256,0,stream>>>(x, w_in, sage_wl, sage_wr, attn_iw,
      attn_ow, mlp_w1, mlp_w2, castb, edst, deg);
  k_scan<<<1,1024,0,stream>>>(deg, offs, inv_deg);

  // CSR fill ∪ in_proj (both ready after scan)
  k_fill_inproj<<<1024,256,0,stream>>>(esrc, edst, offs, cursor, csr,
      xb, w_in_b, b_in, hwb);

  for(int l=0; l<NLAYERS; ++l){
    const ushort* swb = sageWb + (size_t)l*131072;   // [256][512] = [wl|wr]
    const ushort* iwb = iw_b + (size_t)l*196608;
    const ushort* owb = ow_b + (size_t)l*65536;
    const ushort* w1b = w1_b + (size_t)l*131072;
    const ushort* w2b = w2_b + (size_t)l*131072;
    float* slot = bnslots + (size_t)l*1536;

    // D1: aggregate ∪ QKV GEMM (packed q/k/v output)
    k_agg_qkv<<<3584,256,0,stream>>>(hwb, offs, csr, inv_deg, iwb,
        attn_ib + l*3*DIM, qpack, kpack, vpack);

    // D2: attention (packed input) ∪ SAGE GEMM (bf16 H resid, BN1 stats)
    k_attn_sage<<<1536,256,0,stream>>>(qpack, kpack, vpack, attnOb, hwb, swb,
        sage_bl + l*DIM, locB, slot, slot+256);

    // out-proj (+bf16 H resid, BN2 stats) -> globB
    k_mm<false,true,true,true,true><<<dim3(4,128),256,0,stream>>>(
        attnOb, owb, attn_ob + l*DIM, hwb+256, globB, slot+512, slot+768,
        N_NODES, DIM, DIM, DIM, DIM, 512);

    // comb = BN1(loc) + BN2(glob)
    k_apply12<<<2048,256,0,stream>>>(locB, globB, slot,
        n1_w + l*DIM, n1_b + l*DIM, n2_w + l*DIM, n2_b + l*DIM, combb);

    // MLP1: hid = relu(comb@w1^T+b1) -> hidb
    k_mm<true,false,true,true,false><<<dim3(8,128),256,0,stream>>>(
        combb, w1b, mlp_b1 + l*DFF, nullptr, hidb, nullptr, nullptr,
        N_NODES, DFF, DIM, DIM, 512, 256);

    // MLP2: out2 = comb + hid@w2^T + b2 (+BN3 stats) -> globB
    k_mm<false,true,true,true,true><<<dim3(4,128),256,0,stream>>>(
        hidb, w2b, mlp_b2 + l*DIM, combb, globB, slot+1024, slot+1280,
        N_NODES, DIM, 512, 512, DIM, 256);

    // BN3 + outer BN + relu + residual -> hwb right half (bf16 H)
    k_apply3o<<<2048,256,0,stream>>>(globB, slot, n3_w + l*DIM,
        bn_w + l*DIM, bn_b + l*DIM, hwb+256);
  }

  k_pool<<<dim3(BGRAPH, NPG/64),256,0,stream>>>(hwb+256, pooled);
  k_out<<<1,512,0,stream>>>(pooled, w_out, b_out, (float*)d_out);
}